// Round 3
// baseline (357.412 us; speedup 1.0000x reference)
//
#include <hip/hip_runtime.h>
#include <hip/hip_bf16.h>

constexpr int BB = 32;     // batches
constexpr int P  = 1024;   // patches per batch
constexpr int O  = 128;    // objects per batch
constexpr int D  = 512;    // feature dim
constexpr float EPS = 1e-8f;
constexpr float SCL = 14.426950408889634f; // (1/0.1) * log2(e)

typedef __attribute__((ext_vector_type(8))) short short8;
typedef __attribute__((ext_vector_type(16))) float f32x16;

__device__ __forceinline__ unsigned short f2bf(float f) {
  __hip_bfloat16 h = __float2bfloat16(f);
  unsigned short u;
  __builtin_memcpy(&u, &h, sizeof(u));
  return u;
}

__device__ __forceinline__ void gld_lds16(const void* g, void* l) {
  __builtin_amdgcn_global_load_lds(
      (const __attribute__((address_space(1))) void*)g,
      (__attribute__((address_space(3))) void*)l, 16, 0, 0);
}

// ---------------- prep: normalized bf16 features into workspace ------------
__global__ __launch_bounds__(256) void prep_kernel(
    const float* __restrict__ pf, const float* __restrict__ of,
    __hip_bfloat16* __restrict__ pn, __hip_bfloat16* __restrict__ on) {
  int lane = threadIdx.x & 63;
  int row = blockIdx.x * 4 + (threadIdx.x >> 6);
  const float* src;
  __hip_bfloat16* dst;
  if (row < BB * P) {
    src = pf + (size_t)row * D;
    dst = pn + (size_t)row * D;
  } else {
    int r = row - BB * P;
    if (r >= BB * O) return;
    src = of + (size_t)r * D;
    dst = on + (size_t)r * D;
  }
  float4 v0 = *(const float4*)(src + lane * 8);
  float4 v1 = *(const float4*)(src + lane * 8 + 4);
  float ss = v0.x * v0.x + v0.y * v0.y + v0.z * v0.z + v0.w * v0.w +
             v1.x * v1.x + v1.y * v1.y + v1.z * v1.z + v1.w * v1.w;
  #pragma unroll
  for (int s = 1; s < 64; s <<= 1) ss += __shfl_xor(ss, s);
  float sc = 1.0f / fmaxf(sqrtf(ss), 1e-12f);
  short8 w;
  w[0] = (short)f2bf(v0.x * sc); w[1] = (short)f2bf(v0.y * sc);
  w[2] = (short)f2bf(v0.z * sc); w[3] = (short)f2bf(v0.w * sc);
  w[4] = (short)f2bf(v1.x * sc); w[5] = (short)f2bf(v1.y * sc);
  w[6] = (short)f2bf(v1.z * sc); w[7] = (short)f2bf(v1.w * sc);
  *reinterpret_cast<short8*>(dst + lane * 8) = w;
}

// --------- main v3: PT=32, grid 1024, 2-phase dbuf pipeline, no mask LDS ---
__global__ __launch_bounds__(256, 3) void icl_main3(
    const __hip_bfloat16* __restrict__ pn, const __hip_bfloat16* __restrict__ on,
    const float* __restrict__ e1i, const float* __restrict__ e1j,
    const float* __restrict__ e2j, float* __restrict__ accum) {

  // XOR-swizzled bf16 tiles; 16B chunk c of row r lives at chunk (c ^ (r&7))
  __shared__ __hip_bfloat16 As[2][32 * 64];    // 2 x 4 KB
  __shared__ __hip_bfloat16 Bs[2][128 * 64];   // 2 x 16 KB
  __shared__ float d_l[4][32], s2_l[4][32], s1_l[4][32], mv_l[4][32];
  __shared__ int   mi_l[4][32], ip_l[4][32];

  const int tid  = threadIdx.x;
  const int lane = tid & 63;
  const int wid  = tid >> 6;   // wave = col-group: cols wid*32..+31 of tile
  const int half = lane >> 5;
  const int l31  = lane & 31;

  const int b    = blockIdx.x & 31;   // batch b -> XCD b%8 (L2 panel reuse)
  const int pt   = blockIdx.x >> 5;   // 32 row-tiles
  const int row0 = pt * 32;

  const __hip_bfloat16* pnb  = pn + (size_t)b * P * D;
  const __hip_bfloat16* onb  = on + (size_t)b * O * D;
  const __hip_bfloat16* arow = pnb + (size_t)row0 * D;
  const size_t rbase = (size_t)b * P + row0;

  // per-thread invariant staging offsets (elements)
  const int s_rrA = tid >> 3, s_cA = tid & 7;
  const int aoff  = s_rrA * D + ((s_cA ^ (s_rrA & 7)) << 3);

  float s1p[16];
  #pragma unroll
  for (int r = 0; r < 16; ++r) s1p[r] = 0.f;

  auto stageA = [&](int buf, int k0) {
    gld_lds16(arow + aoff + k0, (char*)&As[buf][0] + (size_t)wid * 1024);
  };
  auto stageB = [&](int buf, const __hip_bfloat16* bsrc, int k0) {
    #pragma unroll
    for (int i = 0; i < 4; ++i) {
      int q = i * 256 + tid;
      int rr = q >> 3, c = q & 7;
      int gc = c ^ (rr & 7);
      gld_lds16(bsrc + (size_t)rr * D + k0 + (gc << 3),
                (char*)&Bs[buf][0] + (size_t)(i * 4096 + wid * 1024));
    }
  };

  // prologue: stage step 0 into buf 0
  stageA(0, 0);
  stageB(0, onb, 0);
  __syncthreads();

  f32x16 acc;
  int cur = 0;
  const int col_in_tile = wid * 32 + l31;

  for (int step = 0; step < 72; ++step) {
    const int ct = step >> 3, ks = step & 7;

    // issue next step's staging into the other buffer (flies under compute)
    if (step < 71) {
      const int ns = step + 1;
      const int nct = ns >> 3, nks = ns & 7;
      const __hip_bfloat16* nb = (nct == 0) ? onb : pnb + (size_t)(nct - 1) * 128 * D;
      stageA(cur ^ 1, nks * 64);
      stageB(cur ^ 1, nb, nks * 64);
    }

    if (ks == 0) {
      #pragma unroll
      for (int k = 0; k < 16; ++k) acc[k] = 0.f;
    }

    #pragma unroll
    for (int kc = 0; kc < 4; ++kc) {
      const int ch = (kc << 1) | half;
      short8 af = *reinterpret_cast<const short8*>(
          &As[cur][l31 * 64 + ((ch ^ (l31 & 7)) << 3)]);
      short8 bfr = *reinterpret_cast<const short8*>(
          &Bs[cur][col_in_tile * 64 + ((ch ^ (l31 & 7)) << 3)]);
      acc = __builtin_amdgcn_mfma_f32_32x32x16_bf16(af, bfr, acc, 0, 0, 0);
    }

    if (ks == 7) {
      if (ct == 0) {
        // objects tile: delta, s2, one-hot position, argmax
        #pragma unroll
        for (int r = 0; r < 16; ++r) {
          const int lrow = (r & 3) + ((r >> 2) << 3) + (half << 2);
          const int col = col_in_tile;
          const size_t gb = (rbase + lrow) * O + col;
          float sim = acc[r];
          float e = exp2f(sim * SCL);
          float v1 = e1i[gb];
          float v2 = e2j[gb];
          float dsum = v1 * e;
          float s2s  = v2 * e;
          int   ipos = (v1 > 0.5f) ? col : -1;
          float mval = sim;
          int   midx = col;
          #pragma unroll
          for (int s = 1; s < 32; s <<= 1) {
            dsum += __shfl_xor(dsum, s);
            s2s  += __shfl_xor(s2s, s);
            ipos  = max(ipos, __shfl_xor(ipos, s));
            float ov = __shfl_xor(mval, s);
            int   oi = __shfl_xor(midx, s);
            if (ov > mval || (ov == mval && oi < midx)) { mval = ov; midx = oi; }
          }
          if (l31 == 0) {
            d_l[wid][lrow] = dsum;
            s2_l[wid][lrow] = s2s;
            mv_l[wid][lrow] = mval;
            mi_l[wid][lrow] = midx;
            ip_l[wid][lrow] = ipos;
          }
        }
      } else {
        // patch tile: s1 partials stay in registers (reduced once at end)
        const int qcol = (ct - 1) * 128 + col_in_tile;
        #pragma unroll
        for (int r = 0; r < 16; ++r) {
          const int lrow = (r & 3) + ((r >> 2) << 3) + (half << 2);
          s1p[r] += e1j[(rbase + lrow) * P + qcol] * exp2f(acc[r] * SCL);
        }
      }
    }

    __syncthreads();   // drains next-step staging; protects buffer swap
    cur ^= 1;
  }

  // reduce s1 partials across the 32-lane groups -> LDS
  #pragma unroll
  for (int r = 0; r < 16; ++r) {
    float v = s1p[r];
    #pragma unroll
    for (int s = 1; s < 32; s <<= 1) v += __shfl_xor(v, s);
    if (l31 == 0) {
      const int lrow = (r & 3) + ((r >> 2) << 3) + (half << 2);
      s1_l[wid][lrow] = v;
    }
  }
  __syncthreads();

  // per-row loss + label (rows 0..31 on wave 0), then atomics
  if (tid < 32) {
    float delta = 0.f, s2 = 0.f, s1 = 0.f;
    float mval = -1e30f;
    int midx = 0, ipos = -1;
    #pragma unroll
    for (int wc = 0; wc < 4; ++wc) {      // ascending col order: tie -> low col
      delta += d_l[wc][tid];
      s2    += s2_l[wc][tid];
      s1    += s1_l[wc][tid];
      ipos   = max(ipos, ip_l[wc][tid]);
      if (mv_l[wc][tid] > mval) { mval = mv_l[wc][tid]; midx = mi_l[wc][tid]; }
    }
    float valid = (ipos >= 0) ? 1.f : 0.f;
    float ratio = delta / (delta + s1 + s2 + EPS);
    float lsum = -logf(ratio + EPS) * valid;
    float lbl  = (midx == ipos) ? valid : 0.f;
    float vct  = valid;
    #pragma unroll
    for (int s = 1; s < 32; s <<= 1) {
      lsum += __shfl_xor(lsum, s);
      lbl  += __shfl_xor(lbl, s);
      vct  += __shfl_xor(vct, s);
    }
    if (tid == 0) {
      atomicAdd(&accum[0], lsum);
      atomicAdd(&accum[1], lbl);
      atomicAdd(&accum[2], vct);
    }
  }
}

// ---------------- fallback path (round-1, known correct) -------------------
__global__ __launch_bounds__(256) void norm_kernel(
    const float* __restrict__ pf, const float* __restrict__ of,
    float* __restrict__ invp, float* __restrict__ invo) {
  int lane = threadIdx.x & 63;
  int row = blockIdx.x * 4 + (threadIdx.x >> 6);
  const float* src;
  float* dst;
  if (row < BB * P) {
    src = pf + (size_t)row * D;
    dst = invp + row;
  } else {
    int r = row - BB * P;
    if (r >= BB * O) return;
    src = of + (size_t)r * D;
    dst = invo + r;
  }
  float ss = 0.f;
  #pragma unroll
  for (int i = 0; i < 2; ++i) {
    float4 v = *(const float4*)(src + (lane + 64 * i) * 4);
    ss += v.x * v.x + v.y * v.y + v.z * v.z + v.w * v.w;
  }
  #pragma unroll
  for (int s = 1; s < 64; s <<= 1) ss += __shfl_xor(ss, s);
  if (lane == 0) *dst = 1.0f / fmaxf(sqrtf(ss), 1e-12f);
}

__global__ __launch_bounds__(256) void icl_main_v1(
    const float* __restrict__ pf, const float* __restrict__ of,
    const float* __restrict__ e1i, const float* __restrict__ e1j,
    const float* __restrict__ e2j, const float* __restrict__ invp,
    const float* __restrict__ invo, float* __restrict__ accum) {
  constexpr int PT = 128, BK = 64;
  __shared__ __hip_bfloat16 As[PT * BK];
  __shared__ __hip_bfloat16 Bs[PT * BK];
  __shared__ float d_l[2][PT], s2_l[2][PT], ei_l[2][PT], s1_l[2][PT], mv_l[2][PT];
  __shared__ int   mi_l[2][PT];
  __shared__ float red[12];

  const int tid  = threadIdx.x;
  const int lane = tid & 63;
  const int wid  = tid >> 6;
  const int wr   = wid >> 1;
  const int wc   = wid & 1;
  const int half = lane >> 5;
  const int l31  = lane & 31;
  const int b    = blockIdx.x & 31;
  const int pt   = blockIdx.x >> 5;
  const int row0 = pt * PT;

  const float* pfb = pf + (size_t)b * P * D;
  const float* ofb = of + (size_t)b * O * D;
  const float* ivp = invp + b * P + row0;
  const float* ivq = invp + b * P;
  const float* ivo = invo + b * O;

  float s1p[2][16];
  #pragma unroll
  for (int m = 0; m < 2; ++m)
    #pragma unroll
    for (int r = 0; r < 16; ++r) s1p[m][r] = 0.f;

  auto stage = [&](const float* __restrict__ src, const float* __restrict__ inv,
                   __hip_bfloat16* __restrict__ lds, int k0) {
    #pragma unroll
    for (int i = 0; i < 8; ++i) {
      int c = i * 256 + tid;
      int rr = c >> 4, kc = c & 15;
      float4 v = *(const float4*)(src + (size_t)rr * D + k0 + (kc << 2));
      float s = inv[rr];
      int off = rr * BK + ((((kc >> 1) ^ (rr & 7)) << 3) | ((kc & 1) << 2));
      ushort4 w;
      w.x = f2bf(v.x * s);
      w.y = f2bf(v.y * s);
      w.z = f2bf(v.z * s);
      w.w = f2bf(v.w * s);
      *reinterpret_cast<ushort4*>(lds + off) = w;
    }
  };

  for (int ct = 0; ct < 9; ++ct) {
    const float* bsrc = (ct == 0) ? ofb : pfb + (size_t)(ct - 1) * 128 * D;
    const float* binv = (ct == 0) ? ivo : ivq + (ct - 1) * 128;

    f32x16 acc[2][2];
    #pragma unroll
    for (int m = 0; m < 2; ++m)
      #pragma unroll
      for (int n = 0; n < 2; ++n)
        #pragma unroll
        for (int k = 0; k < 16; ++k) acc[m][n][k] = 0.f;

    for (int ks = 0; ks < D / BK; ++ks) {
      __syncthreads();
      stage(pfb + (size_t)row0 * D, ivp, As, ks * BK);
      stage(bsrc, binv, Bs, ks * BK);
      __syncthreads();
      #pragma unroll
      for (int kc = 0; kc < 4; ++kc) {
        short8 af[2], bfr[2];
        #pragma unroll
        for (int m = 0; m < 2; ++m) {
          int row = wr * 64 + m * 32 + l31;
          af[m] = *reinterpret_cast<const short8*>(
              As + row * BK + ((((kc << 1) | half) ^ (row & 7)) << 3));
        }
        #pragma unroll
        for (int n = 0; n < 2; ++n) {
          int col = wc * 64 + n * 32 + l31;
          bfr[n] = *reinterpret_cast<const short8*>(
              Bs + col * BK + ((((kc << 1) | half) ^ (col & 7)) << 3));
        }
        #pragma unroll
        for (int m = 0; m < 2; ++m)
          #pragma unroll
          for (int n = 0; n < 2; ++n)
            acc[m][n] = __builtin_amdgcn_mfma_f32_32x32x16_bf16(
                af[m], bfr[n], acc[m][n], 0, 0, 0);
      }
    }

    if (ct == 0) {
      #pragma unroll
      for (int m = 0; m < 2; ++m) {
        #pragma unroll
        for (int r = 0; r < 16; ++r) {
          int lrow = wr * 64 + m * 32 + (r & 3) + ((r >> 2) << 3) + (half << 2);
          size_t base = ((size_t)b * P + row0 + lrow) * O;
          float dsum = 0.f, s2s = 0.f, eis = 0.f, mval = -1e30f;
          int midx = 0;
          #pragma unroll
          for (int n = 0; n < 2; ++n) {
            int col = wc * 64 + n * 32 + l31;
            float sim = acc[m][n][r];
            float e = exp2f(sim * SCL);
            float v1 = e1i[base + col];
            float v2 = e2j[base + col];
            dsum += v1 * e;
            s2s  += v2 * e;
            eis  += v1;
            if (sim > mval) { mval = sim; midx = col; }
          }
          #pragma unroll
          for (int s = 1; s < 32; s <<= 1) {
            dsum += __shfl_xor(dsum, s);
            s2s  += __shfl_xor(s2s, s);
            eis  += __shfl_xor(eis, s);
            float ov = __shfl_xor(mval, s);
            int   oi = __shfl_xor(midx, s);
            if (ov > mval || (ov == mval && oi < midx)) { mval = ov; midx = oi; }
          }
          if (l31 == 0) {
            d_l[wc][lrow] = dsum;
            s2_l[wc][lrow] = s2s;
            ei_l[wc][lrow] = eis;
            mv_l[wc][lrow] = mval;
            mi_l[wc][lrow] = midx;
          }
        }
      }
    } else {
      const int qbase = (ct - 1) * 128;
      #pragma unroll
      for (int m = 0; m < 2; ++m) {
        #pragma unroll
        for (int r = 0; r < 16; ++r) {
          int lrow = wr * 64 + m * 32 + (r & 3) + ((r >> 2) << 3) + (half << 2);
          size_t base = ((size_t)b * P + row0 + lrow) * P + qbase;
          float s = 0.f;
          #pragma unroll
          for (int n = 0; n < 2; ++n) {
            int col = wc * 64 + n * 32 + l31;
            s += e1j[base + col] * exp2f(acc[m][n][r] * SCL);
          }
          s1p[m][r] += s;
        }
      }
    }
  }

  #pragma unroll
  for (int m = 0; m < 2; ++m) {
    #pragma unroll
    for (int r = 0; r < 16; ++r) {
      float v = s1p[m][r];
      #pragma unroll
      for (int s = 1; s < 32; s <<= 1) v += __shfl_xor(v, s);
      if (l31 == 0) {
        int lrow = wr * 64 + m * 32 + (r & 3) + ((r >> 2) << 3) + (half << 2);
        s1_l[wc][lrow] = v;
      }
    }
  }
  __syncthreads();

  float lsum = 0.f, lbl = 0.f, vct = 0.f;
  if (tid < PT) {
    float delta = d_l[0][tid] + d_l[1][tid];
    float s2 = s2_l[0][tid] + s2_l[1][tid];
    float eis = ei_l[0][tid] + ei_l[1][tid];
    float s1 = s1_l[0][tid] + s1_l[1][tid];
    float m0 = mv_l[0][tid], m1 = mv_l[1][tid];
    int mi = (m1 > m0) ? mi_l[1][tid] : mi_l[0][tid];
    float valid = (eis > 0.f) ? 1.f : 0.f;
    float ratio = delta / (delta + s1 + s2 + EPS);
    float loss = -logf(ratio + EPS);
    float label = e1i[((size_t)b * P + row0 + tid) * O + mi];
    lsum = loss * valid;
    lbl  = label * valid;
    vct  = valid;
  }
  #pragma unroll
  for (int s = 1; s < 64; s <<= 1) {
    lsum += __shfl_xor(lsum, s);
    lbl  += __shfl_xor(lbl, s);
    vct  += __shfl_xor(vct, s);
  }
  if (lane == 0) {
    red[wid * 3 + 0] = lsum;
    red[wid * 3 + 1] = lbl;
    red[wid * 3 + 2] = vct;
  }
  __syncthreads();
  if (tid == 0) {
    float a = red[0] + red[3] + red[6] + red[9];
    float c = red[1] + red[4] + red[7] + red[10];
    float v = red[2] + red[5] + red[8] + red[11];
    atomicAdd(&accum[0], a);
    atomicAdd(&accum[1], c);
    atomicAdd(&accum[2], v);
  }
}

__global__ void finalize_kernel(const float* __restrict__ accum,
                                float* __restrict__ out) {
  if (threadIdx.x == 0 && blockIdx.x == 0) {
    float nv = accum[2];
    out[0] = accum[0] / nv;
    out[1] = accum[1] / nv;
  }
}

extern "C" void kernel_launch(void* const* d_in, const int* in_sizes, int n_in,
                              void* d_out, int out_size, void* d_ws, size_t ws_size,
                              hipStream_t stream) {
  const float* pf  = (const float*)d_in[0];
  const float* of  = (const float*)d_in[1];
  const float* e1i = (const float*)d_in[2];
  const float* e1j = (const float*)d_in[3];
  const float* e2j = (const float*)d_in[4];

  float* ws    = (float*)d_ws;
  float* accum = ws;  // [0]=loss_sum [1]=label_sum [2]=valid_sum
  hipMemsetAsync(accum, 0, 16 * sizeof(float), stream);

  const size_t pn_bytes = (size_t)BB * P * D * 2;
  const size_t on_bytes = (size_t)BB * O * D * 2;
  const size_t need = 64 + pn_bytes + on_bytes;

  if (ws_size >= need) {
    __hip_bfloat16* pn = (__hip_bfloat16*)((char*)d_ws + 64);
    __hip_bfloat16* on = (__hip_bfloat16*)((char*)d_ws + 64 + pn_bytes);
    prep_kernel<<<(BB * P + BB * O) / 4, 256, 0, stream>>>(pf, of, pn, on);
    icl_main3<<<BB * (P / 32), 256, 0, stream>>>(pn, on, e1i, e1j, e2j, accum);
  } else {
    float* invp = ws + 16;
    float* invo = ws + 16 + BB * P;
    norm_kernel<<<(BB * P + BB * O) / 4, 256, 0, stream>>>(pf, of, invp, invo);
    icl_main_v1<<<BB * (P / 128), 256, 0, stream>>>(pf, of, e1i, e1j, e2j, invp, invo, accum);
  }
  finalize_kernel<<<1, 64, 0, stream>>>(accum, (float*)d_out);
}

// Round 4
// 304.652 us; speedup vs baseline: 1.1732x; 1.1732x over previous
//
#include <hip/hip_runtime.h>
#include <hip/hip_bf16.h>

constexpr int BB = 32;     // batches
constexpr int P  = 1024;   // patches per batch
constexpr int O  = 128;    // objects per batch
constexpr int D  = 512;    // feature dim
constexpr float EPS = 1e-8f;
constexpr float SCL = 14.426950408889634f; // (1/0.1) * log2(e)

typedef __attribute__((ext_vector_type(8))) short short8;
typedef __attribute__((ext_vector_type(16))) float f32x16;

__device__ __forceinline__ unsigned short f2bf(float f) {
  __hip_bfloat16 h = __float2bfloat16(f);
  unsigned short u;
  __builtin_memcpy(&u, &h, sizeof(u));
  return u;
}

__device__ __forceinline__ void gld_lds16(const void* g, void* l) {
  __builtin_amdgcn_global_load_lds(
      (const __attribute__((address_space(1))) void*)g,
      (__attribute__((address_space(3))) void*)l, 16, 0, 0);
}

// ---------------- prep: normalized bf16 features into workspace ------------
__global__ __launch_bounds__(256) void prep_kernel(
    const float* __restrict__ pf, const float* __restrict__ of,
    __hip_bfloat16* __restrict__ pn, __hip_bfloat16* __restrict__ on) {
  int lane = threadIdx.x & 63;
  int row = blockIdx.x * 4 + (threadIdx.x >> 6);
  const float* src;
  __hip_bfloat16* dst;
  if (row < BB * P) {
    src = pf + (size_t)row * D;
    dst = pn + (size_t)row * D;
  } else {
    int r = row - BB * P;
    if (r >= BB * O) return;
    src = of + (size_t)r * D;
    dst = on + (size_t)r * D;
  }
  float4 v0 = *(const float4*)(src + lane * 8);
  float4 v1 = *(const float4*)(src + lane * 8 + 4);
  float ss = v0.x * v0.x + v0.y * v0.y + v0.z * v0.z + v0.w * v0.w +
             v1.x * v1.x + v1.y * v1.y + v1.z * v1.z + v1.w * v1.w;
  #pragma unroll
  for (int s = 1; s < 64; s <<= 1) ss += __shfl_xor(ss, s);
  float sc = 1.0f / fmaxf(sqrtf(ss), 1e-12f);
  short8 w;
  w[0] = (short)f2bf(v0.x * sc); w[1] = (short)f2bf(v0.y * sc);
  w[2] = (short)f2bf(v0.z * sc); w[3] = (short)f2bf(v0.w * sc);
  w[4] = (short)f2bf(v1.x * sc); w[5] = (short)f2bf(v1.y * sc);
  w[6] = (short)f2bf(v1.z * sc); w[7] = (short)f2bf(v1.w * sc);
  *reinterpret_cast<short8*>(dst + lane * 8) = w;
}

// ---- main v4: B-in-LDS for full K, A streamed to VGPR, 1 barrier/col-tile --
// block = 4 waves = 128 rows (wave owns 32 rows); 36 col-tiles of 32 cols
// (tiles 0..3 = objects, 4..35 = patches). grid = 32 batches x 8 row-tiles.
__global__ __launch_bounds__(256, 1) void icl_main4(
    const __hip_bfloat16* __restrict__ pn, const __hip_bfloat16* __restrict__ on,
    const float* __restrict__ e1i, const float* __restrict__ e1j,
    const float* __restrict__ e2j, float* __restrict__ accum) {

  // [col][K] bf16, XOR-swizzled 16B chunks: chunk c of col q stored at c^(q&7)
  __shared__ __hip_bfloat16 Bs[2][32 * 512];   // 2 x 32 KB

  const int tid  = threadIdx.x;
  const int l    = tid & 63;
  const int wid  = tid >> 6;
  const int half = l >> 5;
  const int l31  = l & 31;

  const int b    = blockIdx.x & 31;   // batch -> XCD b%8 (panel L2 reuse)
  const int rt   = blockIdx.x >> 5;   // 8 row tiles of 128
  const int row0 = rt * 128 + wid * 32;     // wave's 32 rows

  const __hip_bfloat16* pnb = pn + (size_t)b * P * D;
  const __hip_bfloat16* onb = on + (size_t)b * O * D;

  // A fragment base: lane reads row (row0+l31), k-sub (half*8)
  const __hip_bfloat16* abase = pnb + (size_t)(row0 + l31) * D + half * 8;

  // stage one 32-col x 512-K tile (32 KB): inst i covers col q = i*4+wid
  auto stageB = [&](int buf, const __hip_bfloat16* csrc) {
    #pragma unroll
    for (int i = 0; i < 8; ++i) {
      const int q = i * 4 + wid;                 // wave-uniform col
      gld_lds16(csrc + (size_t)q * D + ((l ^ (q & 7)) << 3),
                (char*)&Bs[buf][0] + q * 1024);
    }
  };
  auto colsrc = [&](int ct) -> const __hip_bfloat16* {
    return (ct < 4) ? onb + (size_t)ct * 32 * D
                    : pnb + (size_t)(ct - 4) * 32 * D;
  };

  // per-lane running accumulators (constant-indexed -> registers)
  float dsum[16], s2p[16], s1p[16], mv[16];
  int   mi[16], ip[16];
  #pragma unroll
  for (int r = 0; r < 16; ++r) {
    dsum[r] = 0.f; s2p[r] = 0.f; s1p[r] = 0.f;
    mv[r] = -1e30f; mi[r] = 0; ip[r] = -1;
  }

  stageB(0, colsrc(0));
  __syncthreads();
  int cur = 0;

  const char* bs_lane_base0 = (const char*)&Bs[0][0] + l31 * 1024;
  const char* bs_lane_base1 = (const char*)&Bs[1][0] + l31 * 1024;
  const int   bswz = l31 & 7;

  for (int ct = 0; ct < 36; ++ct) {
    // issue next tile's staging; completes during this tile's K-loop
    if (ct < 35) stageB(cur ^ 1, colsrc(ct + 1));

    f32x16 acc;
    #pragma unroll
    for (int k = 0; k < 16; ++k) acc[k] = 0.f;

    const char* bbase = cur ? bs_lane_base1 : bs_lane_base0;
    #pragma unroll
    for (int s = 0; s < 32; ++s) {
      short8 af = *reinterpret_cast<const short8*>(abase + s * 16);
      short8 bf = *reinterpret_cast<const short8*>(
          bbase + ((((s << 1) | half) ^ bswz) << 4));
      acc = __builtin_amdgcn_mfma_f32_32x32x16_bf16(af, bf, acc, 0, 0, 0);
    }

    if (ct < 4) {
      const int col = ct * 32 + l31;
      #pragma unroll
      for (int r = 0; r < 16; ++r) {
        const int lrow = (r & 3) + ((r >> 2) << 3) + (half << 2);
        const size_t g = ((size_t)b * P + row0 + lrow) * O + col;
        float sim = acc[r];
        float e = exp2f(sim * SCL);
        float v1 = e1i[g];
        float v2 = e2j[g];
        dsum[r] += v1 * e;
        s2p[r]  += v2 * e;
        if (v1 > 0.5f) ip[r] = col;                       // one-hot position
        if (sim > mv[r]) { mv[r] = sim; mi[r] = col; }    // first-max kept
      }
    } else {
      const int col = (ct - 4) * 32 + l31;
      #pragma unroll
      for (int r = 0; r < 16; ++r) {
        const int lrow = (r & 3) + ((r >> 2) << 3) + (half << 2);
        const size_t g = ((size_t)b * P + row0 + lrow) * P + col;
        s1p[r] += e1j[g] * exp2f(acc[r] * SCL);
      }
    }

    __syncthreads();   // all waves done reading Bs[cur]; stage long complete
    cur ^= 1;
  }

  // final per-row reduce across the 32-lane col groups, then wave atomics
  float lsum = 0.f, lbl = 0.f, vct = 0.f;
  #pragma unroll
  for (int r = 0; r < 16; ++r) {
    float dv = dsum[r], s2v = s2p[r], s1v = s1p[r], mvv = mv[r];
    int miv = mi[r], ipv = ip[r];
    #pragma unroll
    for (int s = 1; s < 32; s <<= 1) {
      dv  += __shfl_xor(dv, s);
      s2v += __shfl_xor(s2v, s);
      s1v += __shfl_xor(s1v, s);
      ipv  = max(ipv, __shfl_xor(ipv, s));
      float ov = __shfl_xor(mvv, s);
      int   oi = __shfl_xor(miv, s);
      if (ov > mvv || (ov == mvv && oi < miv)) { mvv = ov; miv = oi; }
    }
    if (l31 == 0) {
      float valid = (ipv >= 0) ? 1.f : 0.f;
      float ratio = dv / (dv + s1v + s2v + EPS);
      lsum += -logf(ratio + EPS) * valid;
      lbl  += (miv == ipv) ? valid : 0.f;
      vct  += valid;
    }
  }
  #pragma unroll
  for (int s = 1; s < 64; s <<= 1) {
    lsum += __shfl_xor(lsum, s);
    lbl  += __shfl_xor(lbl, s);
    vct  += __shfl_xor(vct, s);
  }
  if (l == 0) {
    atomicAdd(&accum[0], lsum);
    atomicAdd(&accum[1], lbl);
    atomicAdd(&accum[2], vct);
  }
}

// ---------------- fallback path (round-1, known correct) -------------------
__global__ __launch_bounds__(256) void norm_kernel(
    const float* __restrict__ pf, const float* __restrict__ of,
    float* __restrict__ invp, float* __restrict__ invo) {
  int lane = threadIdx.x & 63;
  int row = blockIdx.x * 4 + (threadIdx.x >> 6);
  const float* src;
  float* dst;
  if (row < BB * P) {
    src = pf + (size_t)row * D;
    dst = invp + row;
  } else {
    int r = row - BB * P;
    if (r >= BB * O) return;
    src = of + (size_t)r * D;
    dst = invo + r;
  }
  float ss = 0.f;
  #pragma unroll
  for (int i = 0; i < 2; ++i) {
    float4 v = *(const float4*)(src + (lane + 64 * i) * 4);
    ss += v.x * v.x + v.y * v.y + v.z * v.z + v.w * v.w;
  }
  #pragma unroll
  for (int s = 1; s < 64; s <<= 1) ss += __shfl_xor(ss, s);
  if (lane == 0) *dst = 1.0f / fmaxf(sqrtf(ss), 1e-12f);
}

__global__ __launch_bounds__(256) void icl_main_v1(
    const float* __restrict__ pf, const float* __restrict__ of,
    const float* __restrict__ e1i, const float* __restrict__ e1j,
    const float* __restrict__ e2j, const float* __restrict__ invp,
    const float* __restrict__ invo, float* __restrict__ accum) {
  constexpr int PT = 128, BK = 64;
  __shared__ __hip_bfloat16 As[PT * BK];
  __shared__ __hip_bfloat16 Bs[PT * BK];
  __shared__ float d_l[2][PT], s2_l[2][PT], ei_l[2][PT], s1_l[2][PT], mv_l[2][PT];
  __shared__ int   mi_l[2][PT];
  __shared__ float red[12];

  const int tid  = threadIdx.x;
  const int lane = tid & 63;
  const int wid  = tid >> 6;
  const int wr   = wid >> 1;
  const int wc   = wid & 1;
  const int half = lane >> 5;
  const int l31  = lane & 31;
  const int b    = blockIdx.x & 31;
  const int pt   = blockIdx.x >> 5;
  const int row0 = pt * PT;

  const float* pfb = pf + (size_t)b * P * D;
  const float* ofb = of + (size_t)b * O * D;
  const float* ivp = invp + b * P + row0;
  const float* ivq = invp + b * P;
  const float* ivo = invo + b * O;

  float s1p[2][16];
  #pragma unroll
  for (int m = 0; m < 2; ++m)
    #pragma unroll
    for (int r = 0; r < 16; ++r) s1p[m][r] = 0.f;

  auto stage = [&](const float* __restrict__ src, const float* __restrict__ inv,
                   __hip_bfloat16* __restrict__ lds, int k0) {
    #pragma unroll
    for (int i = 0; i < 8; ++i) {
      int c = i * 256 + tid;
      int rr = c >> 4, kc = c & 15;
      float4 v = *(const float4*)(src + (size_t)rr * D + k0 + (kc << 2));
      float s = inv[rr];
      int off = rr * BK + ((((kc >> 1) ^ (rr & 7)) << 3) | ((kc & 1) << 2));
      ushort4 w;
      w.x = f2bf(v.x * s);
      w.y = f2bf(v.y * s);
      w.z = f2bf(v.z * s);
      w.w = f2bf(v.w * s);
      *reinterpret_cast<ushort4*>(lds + off) = w;
    }
  };

  for (int ct = 0; ct < 9; ++ct) {
    const float* bsrc = (ct == 0) ? ofb : pfb + (size_t)(ct - 1) * 128 * D;
    const float* binv = (ct == 0) ? ivo : ivq + (ct - 1) * 128;

    f32x16 acc[2][2];
    #pragma unroll
    for (int m = 0; m < 2; ++m)
      #pragma unroll
      for (int n = 0; n < 2; ++n)
        #pragma unroll
        for (int k = 0; k < 16; ++k) acc[m][n][k] = 0.f;

    for (int ks = 0; ks < D / BK; ++ks) {
      __syncthreads();
      stage(pfb + (size_t)row0 * D, ivp, As, ks * BK);
      stage(bsrc, binv, Bs, ks * BK);
      __syncthreads();
      #pragma unroll
      for (int kc = 0; kc < 4; ++kc) {
        short8 af[2], bfr[2];
        #pragma unroll
        for (int m = 0; m < 2; ++m) {
          int row = wr * 64 + m * 32 + l31;
          af[m] = *reinterpret_cast<const short8*>(
              As + row * BK + ((((kc << 1) | half) ^ (row & 7)) << 3));
        }
        #pragma unroll
        for (int n = 0; n < 2; ++n) {
          int col = wc * 64 + n * 32 + l31;
          bfr[n] = *reinterpret_cast<const short8*>(
              Bs + col * BK + ((((kc << 1) | half) ^ (col & 7)) << 3));
        }
        #pragma unroll
        for (int m = 0; m < 2; ++m)
          #pragma unroll
          for (int n = 0; n < 2; ++n)
            acc[m][n] = __builtin_amdgcn_mfma_f32_32x32x16_bf16(
                af[m], bfr[n], acc[m][n], 0, 0, 0);
      }
    }

    if (ct == 0) {
      #pragma unroll
      for (int m = 0; m < 2; ++m) {
        #pragma unroll
        for (int r = 0; r < 16; ++r) {
          int lrow = wr * 64 + m * 32 + (r & 3) + ((r >> 2) << 3) + (half << 2);
          size_t base = ((size_t)b * P + row0 + lrow) * O;
          float dsum = 0.f, s2s = 0.f, eis = 0.f, mval = -1e30f;
          int midx = 0;
          #pragma unroll
          for (int n = 0; n < 2; ++n) {
            int col = wc * 64 + n * 32 + l31;
            float sim = acc[m][n][r];
            float e = exp2f(sim * SCL);
            float v1 = e1i[base + col];
            float v2 = e2j[base + col];
            dsum += v1 * e;
            s2s  += v2 * e;
            eis  += v1;
            if (sim > mval) { mval = sim; midx = col; }
          }
          #pragma unroll
          for (int s = 1; s < 32; s <<= 1) {
            dsum += __shfl_xor(dsum, s);
            s2s  += __shfl_xor(s2s, s);
            eis  += __shfl_xor(eis, s);
            float ov = __shfl_xor(mval, s);
            int   oi = __shfl_xor(midx, s);
            if (ov > mval || (ov == mval && oi < midx)) { mval = ov; midx = oi; }
          }
          if (l31 == 0) {
            d_l[wc][lrow] = dsum;
            s2_l[wc][lrow] = s2s;
            ei_l[wc][lrow] = eis;
            mv_l[wc][lrow] = mval;
            mi_l[wc][lrow] = midx;
          }
        }
      }
    } else {
      const int qbase = (ct - 1) * 128;
      #pragma unroll
      for (int m = 0; m < 2; ++m) {
        #pragma unroll
        for (int r = 0; r < 16; ++r) {
          int lrow = wr * 64 + m * 32 + (r & 3) + ((r >> 2) << 3) + (half << 2);
          size_t base = ((size_t)b * P + row0 + lrow) * P + qbase;
          float s = 0.f;
          #pragma unroll
          for (int n = 0; n < 2; ++n) {
            int col = wc * 64 + n * 32 + l31;
            s += e1j[base + col] * exp2f(acc[m][n][r] * SCL);
          }
          s1p[m][r] += s;
        }
      }
    }
  }

  #pragma unroll
  for (int m = 0; m < 2; ++m) {
    #pragma unroll
    for (int r = 0; r < 16; ++r) {
      float v = s1p[m][r];
      #pragma unroll
      for (int s = 1; s < 32; s <<= 1) v += __shfl_xor(v, s);
      if (l31 == 0) {
        int lrow = wr * 64 + m * 32 + (r & 3) + ((r >> 2) << 3) + (half << 2);
        s1_l[wc][lrow] = v;
      }
    }
  }
  __syncthreads();

  float lsum = 0.f, lbl = 0.f, vct = 0.f;
  if (tid < PT) {
    float delta = d_l[0][tid] + d_l[1][tid];
    float s2 = s2_l[0][tid] + s2_l[1][tid];
    float eis = ei_l[0][tid] + ei_l[1][tid];
    float s1 = s1_l[0][tid] + s1_l[1][tid];
    float m0 = mv_l[0][tid], m1 = mv_l[1][tid];
    int mi = (m1 > m0) ? mi_l[1][tid] : mi_l[0][tid];
    float valid = (eis > 0.f) ? 1.f : 0.f;
    float ratio = delta / (delta + s1 + s2 + EPS);
    float loss = -logf(ratio + EPS);
    float label = e1i[((size_t)b * P + row0 + tid) * O + mi];
    lsum = loss * valid;
    lbl  = label * valid;
    vct  = valid;
  }
  #pragma unroll
  for (int s = 1; s < 64; s <<= 1) {
    lsum += __shfl_xor(lsum, s);
    lbl  += __shfl_xor(lbl, s);
    vct  += __shfl_xor(vct, s);
  }
  if (lane == 0) {
    red[wid * 3 + 0] = lsum;
    red[wid * 3 + 1] = lbl;
    red[wid * 3 + 2] = vct;
  }
  __syncthreads();
  if (tid == 0) {
    float a = red[0] + red[3] + red[6] + red[9];
    float c = red[1] + red[4] + red[7] + red[10];
    float v = red[2] + red[5] + red[8] + red[11];
    atomicAdd(&accum[0], a);
    atomicAdd(&accum[1], c);
    atomicAdd(&accum[2], v);
  }
}

__global__ void finalize_kernel(const float* __restrict__ accum,
                                float* __restrict__ out) {
  if (threadIdx.x == 0 && blockIdx.x == 0) {
    float nv = accum[2];
    out[0] = accum[0] / nv;
    out[1] = accum[1] / nv;
  }
}

extern "C" void kernel_launch(void* const* d_in, const int* in_sizes, int n_in,
                              void* d_out, int out_size, void* d_ws, size_t ws_size,
                              hipStream_t stream) {
  const float* pf  = (const float*)d_in[0];
  const float* of  = (const float*)d_in[1];
  const float* e1i = (const float*)d_in[2];
  const float* e1j = (const float*)d_in[3];
  const float* e2j = (const float*)d_in[4];

  float* ws    = (float*)d_ws;
  float* accum = ws;  // [0]=loss_sum [1]=label_sum [2]=valid_sum
  hipMemsetAsync(accum, 0, 16 * sizeof(float), stream);

  const size_t pn_bytes = (size_t)BB * P * D * 2;
  const size_t on_bytes = (size_t)BB * O * D * 2;
  const size_t need = 64 + pn_bytes + on_bytes;

  if (ws_size >= need) {
    __hip_bfloat16* pn = (__hip_bfloat16*)((char*)d_ws + 64);
    __hip_bfloat16* on = (__hip_bfloat16*)((char*)d_ws + 64 + pn_bytes);
    prep_kernel<<<(BB * P + BB * O) / 4, 256, 0, stream>>>(pf, of, pn, on);
    icl_main4<<<BB * (P / 128), 256, 0, stream>>>(pn, on, e1i, e1j, e2j, accum);
  } else {
    float* invp = ws + 16;
    float* invo = ws + 16 + BB * P;
    norm_kernel<<<(BB * P + BB * O) / 4, 256, 0, stream>>>(pf, of, invp, invo);
    icl_main_v1<<<BB * (P / 128), 256, 0, stream>>>(pf, of, e1i, e1j, e2j, invp, invo, accum);
  }
  finalize_kernel<<<1, 64, 0, stream>>>(accum, (float*)d_out);
}

// Round 5
// 180.958 us; speedup vs baseline: 1.9751x; 1.6836x over previous
//
#include <hip/hip_runtime.h>
#include <hip/hip_bf16.h>

constexpr int BB = 32;     // batches
constexpr int P  = 1024;   // patches per batch
constexpr int O  = 128;    // objects per batch
constexpr int D  = 512;    // feature dim
constexpr float EPS = 1e-8f;
constexpr float SCL = 14.426950408889634f; // (1/0.1) * log2(e)

typedef __attribute__((ext_vector_type(8))) short short8;
typedef __attribute__((ext_vector_type(16))) float f32x16;

__device__ __forceinline__ unsigned short f2bf(float f) {
  __hip_bfloat16 h = __float2bfloat16(f);
  unsigned short u;
  __builtin_memcpy(&u, &h, sizeof(u));
  return u;
}

__device__ __forceinline__ void gld_lds16(const void* g, void* l) {
  __builtin_amdgcn_global_load_lds(
      (const __attribute__((address_space(1))) void*)g,
      (__attribute__((address_space(3))) void*)l, 16, 0, 0);
}

// ---------------- prep: normalized bf16 features into workspace ------------
__global__ __launch_bounds__(256) void prep_kernel(
    const float* __restrict__ pf, const float* __restrict__ of,
    __hip_bfloat16* __restrict__ pn, __hip_bfloat16* __restrict__ on) {
  int lane = threadIdx.x & 63;
  int row = blockIdx.x * 4 + (threadIdx.x >> 6);
  const float* src;
  __hip_bfloat16* dst;
  if (row < BB * P) {
    src = pf + (size_t)row * D;
    dst = pn + (size_t)row * D;
  } else {
    int r = row - BB * P;
    if (r >= BB * O) return;
    src = of + (size_t)r * D;
    dst = on + (size_t)r * D;
  }
  float4 v0 = *(const float4*)(src + lane * 8);
  float4 v1 = *(const float4*)(src + lane * 8 + 4);
  float ss = v0.x * v0.x + v0.y * v0.y + v0.z * v0.z + v0.w * v0.w +
             v1.x * v1.x + v1.y * v1.y + v1.z * v1.z + v1.w * v1.w;
  #pragma unroll
  for (int s = 1; s < 64; s <<= 1) ss += __shfl_xor(ss, s);
  float sc = 1.0f / fmaxf(sqrtf(ss), 1e-12f);
  short8 w;
  w[0] = (short)f2bf(v0.x * sc); w[1] = (short)f2bf(v0.y * sc);
  w[2] = (short)f2bf(v0.z * sc); w[3] = (short)f2bf(v0.w * sc);
  w[4] = (short)f2bf(v1.x * sc); w[5] = (short)f2bf(v1.y * sc);
  w[6] = (short)f2bf(v1.z * sc); w[7] = (short)f2bf(v1.w * sc);
  *reinterpret_cast<short8*>(dst + lane * 8) = w;
}

// ---- main v5: B-panel resident in LDS, barrier-free K-loop, 2 blocks/CU ---
// grid = 32 batches x 18 stripes(64 cols) x 2 row-halves = 1152 blocks.
// stripes 0,1 = objects (cols 0..127), stripes 2..17 = patches.
// block = 8 waves; per pass each wave owns 32 rows x 64 cols; 2 passes.
__global__ __launch_bounds__(512, 4) void icl_main5(
    const __hip_bfloat16* __restrict__ pn, const __hip_bfloat16* __restrict__ on,
    const float* __restrict__ e1i, const float* __restrict__ e1j,
    const float* __restrict__ e2j,
    float* __restrict__ d_row, float* __restrict__ s1_row,
    float* __restrict__ s2_row, unsigned long long* __restrict__ pk_row,
    int* __restrict__ ip_row) {

  // [kc 0..63][col 0..63] 16B chunks; chunk(kc,col) holds B[col][kc*8..+8].
  // ds_read: 32 lanes read consecutive cols -> contiguous 512B, conflict-free.
  __shared__ __hip_bfloat16 Bs[64 * 64 * 8];   // 64 KB

  const int tid  = threadIdx.x;
  const int l    = tid & 63;
  const int wid  = tid >> 6;
  const int half = l >> 5;
  const int l31  = l & 31;

  const int bid    = blockIdx.x;
  const int batch  = bid & 31;            // same-batch blocks share XCD (b%8)
  const int unit   = bid >> 5;            // 0..35
  const int stripe = unit >> 1;           // 0..17
  const int rh     = unit & 1;            // row half: rows [rh*512, rh*512+512)
  const bool isobj = stripe < 2;

  const __hip_bfloat16* pnb = pn + (size_t)batch * P * D;
  const __hip_bfloat16* onb = on + (size_t)batch * O * D;
  const __hip_bfloat16* bsrc =
      isobj ? onb + (size_t)stripe * 64 * D
            : pnb + (size_t)(stripe - 2) * 64 * D;

  // stage B once: chunk idx = kc*64 + col; dest linear in idx (gld_lds ok)
  #pragma unroll
  for (int i = 0; i < 8; ++i) {
    const int idx = i * 512 + tid;
    gld_lds16(bsrc + (size_t)(idx & 63) * D + (idx >> 6) * 8,
              (char*)Bs + (size_t)idx * 16);
  }
  __syncthreads();   // compiler drains vmcnt before barrier: Bs ready

  const int cb = stripe * 64;                   // global col base (obj space)
  const int pb = (stripe - 2) * 64;             // global col base (patch space)

  for (int p = 0; p < 2; ++p) {
    const int rowt = rh * 512 + p * 256 + wid * 32;   // wave's 32-row tile
    const __hip_bfloat16* a0 = pnb + (size_t)(rowt + l31) * D + half * 8;

    f32x16 acc0, acc1;
    #pragma unroll
    for (int k = 0; k < 16; ++k) { acc0[k] = 0.f; acc1[k] = 0.f; }

    #pragma unroll
    for (int s = 0; s < 32; ++s) {
      const char* bb = (const char*)Bs + (((s << 1) | half) << 10);
      short8 b0 = *reinterpret_cast<const short8*>(bb + (l31 << 4));
      short8 b1 = *reinterpret_cast<const short8*>(bb + ((32 + l31) << 4));
      short8 A0 = *reinterpret_cast<const short8*>(a0 + s * 16);
      acc0 = __builtin_amdgcn_mfma_f32_32x32x16_bf16(A0, b0, acc0, 0, 0, 0);
      acc1 = __builtin_amdgcn_mfma_f32_32x32x16_bf16(A0, b1, acc1, 0, 0, 0);
    }

    if (isobj) {
      #pragma unroll
      for (int r = 0; r < 16; ++r) {
        const int lrow = (r & 3) + ((r >> 2) << 3) + (half << 2);
        const size_t grow = (size_t)batch * P + rowt + lrow;
        const size_t gb = grow * O + cb;
        const int c0 = cb + l31, c1 = cb + 32 + l31;
        float s0 = acc0[r], s1v = acc1[r];
        float e0 = exp2f(s0 * SCL), e1 = exp2f(s1v * SCL);
        float m10 = e1i[gb + l31], m11 = e1i[gb + 32 + l31];
        float m20 = e2j[gb + l31], m21 = e2j[gb + 32 + l31];
        float dv  = m10 * e0 + m11 * e1;
        float s2v = m20 * e0 + m21 * e1;
        int ipv = (m11 > 0.5f) ? c1 : ((m10 > 0.5f) ? c0 : -1);
        float mvv; int miv;
        if (s1v > s0) { mvv = s1v; miv = c1; } else { mvv = s0; miv = c0; }
        #pragma unroll
        for (int s = 1; s < 32; s <<= 1) {
          dv  += __shfl_xor(dv, s);
          s2v += __shfl_xor(s2v, s);
          ipv  = max(ipv, __shfl_xor(ipv, s));
          float ov = __shfl_xor(mvv, s);
          int   oi = __shfl_xor(miv, s);
          if (ov > mvv || (ov == mvv && oi < miv)) { mvv = ov; miv = oi; }
        }
        if (l31 == 0) {
          if (dv != 0.f) atomicAdd(&d_row[grow], dv);
          atomicAdd(&s2_row[grow], s2v);
          unsigned long long pkv =
              ((unsigned long long)__float_as_uint(mvv + 2.0f) << 32) |
              (unsigned)(0xFFFFFFFFu - (unsigned)miv);
          atomicMax(&pk_row[grow], pkv);
          if (ipv >= 0) atomicMax(&ip_row[grow], ipv);
        }
      }
    } else {
      #pragma unroll
      for (int r = 0; r < 16; ++r) {
        const int lrow = (r & 3) + ((r >> 2) << 3) + (half << 2);
        const size_t grow = (size_t)batch * P + rowt + lrow;
        const size_t gb = grow * P + pb;
        float v = e1j[gb + l31] * exp2f(acc0[r] * SCL) +
                  e1j[gb + 32 + l31] * exp2f(acc1[r] * SCL);
        #pragma unroll
        for (int s = 1; s < 32; s <<= 1) v += __shfl_xor(v, s);
        if (l31 == 0) atomicAdd(&s1_row[grow], v);
      }
    }
  }
}

// ---------------- per-row loss + scalar reduction --------------------------
__global__ __launch_bounds__(256) void icl_reduce(
    const float* __restrict__ d_row, const float* __restrict__ s1_row,
    const float* __restrict__ s2_row, const unsigned long long* __restrict__ pk_row,
    const int* __restrict__ ip_row, float* __restrict__ accum) {
  __shared__ float red[12];
  const int tid = threadIdx.x;
  const int row = blockIdx.x * 256 + tid;
  float d = d_row[row], a = s1_row[row], c = s2_row[row];
  int ipv = ip_row[row];
  int miv = (int)(0xFFFFFFFFu - (unsigned)(pk_row[row] & 0xFFFFFFFFull));
  float valid = (ipv >= 0) ? 1.f : 0.f;
  float ratio = d / (d + a + c + EPS);
  float lsum = -logf(ratio + EPS) * valid;
  float lbl  = (ipv >= 0 && miv == ipv) ? 1.f : 0.f;
  float vct  = valid;
  #pragma unroll
  for (int s = 1; s < 64; s <<= 1) {
    lsum += __shfl_xor(lsum, s);
    lbl  += __shfl_xor(lbl, s);
    vct  += __shfl_xor(vct, s);
  }
  const int wid = tid >> 6;
  if ((tid & 63) == 0) {
    red[wid * 3 + 0] = lsum;
    red[wid * 3 + 1] = lbl;
    red[wid * 3 + 2] = vct;
  }
  __syncthreads();
  if (tid == 0) {
    atomicAdd(&accum[0], red[0] + red[3] + red[6] + red[9]);
    atomicAdd(&accum[1], red[1] + red[4] + red[7] + red[10]);
    atomicAdd(&accum[2], red[2] + red[5] + red[8] + red[11]);
  }
}

__global__ void finalize_kernel(const float* __restrict__ accum,
                                float* __restrict__ out) {
  if (threadIdx.x == 0 && blockIdx.x == 0) {
    float nv = accum[2];
    out[0] = accum[0] / nv;
    out[1] = accum[1] / nv;
  }
}

// ---------------- fallback path (round-1, known correct) -------------------
__global__ __launch_bounds__(256) void norm_kernel(
    const float* __restrict__ pf, const float* __restrict__ of,
    float* __restrict__ invp, float* __restrict__ invo) {
  int lane = threadIdx.x & 63;
  int row = blockIdx.x * 4 + (threadIdx.x >> 6);
  const float* src;
  float* dst;
  if (row < BB * P) {
    src = pf + (size_t)row * D;
    dst = invp + row;
  } else {
    int r = row - BB * P;
    if (r >= BB * O) return;
    src = of + (size_t)r * D;
    dst = invo + r;
  }
  float ss = 0.f;
  #pragma unroll
  for (int i = 0; i < 2; ++i) {
    float4 v = *(const float4*)(src + (lane + 64 * i) * 4);
    ss += v.x * v.x + v.y * v.y + v.z * v.z + v.w * v.w;
  }
  #pragma unroll
  for (int s = 1; s < 64; s <<= 1) ss += __shfl_xor(ss, s);
  if (lane == 0) *dst = 1.0f / fmaxf(sqrtf(ss), 1e-12f);
}

__global__ __launch_bounds__(256) void icl_main_v1(
    const float* __restrict__ pf, const float* __restrict__ of,
    const float* __restrict__ e1i, const float* __restrict__ e1j,
    const float* __restrict__ e2j, const float* __restrict__ invp,
    const float* __restrict__ invo, float* __restrict__ accum) {
  constexpr int PT = 128, BK = 64;
  __shared__ __hip_bfloat16 As[PT * BK];
  __shared__ __hip_bfloat16 Bs[PT * BK];
  __shared__ float d_l[2][PT], s2_l[2][PT], ei_l[2][PT], s1_l[2][PT], mv_l[2][PT];
  __shared__ int   mi_l[2][PT];
  __shared__ float red[12];

  const int tid  = threadIdx.x;
  const int lane = tid & 63;
  const int wid  = tid >> 6;
  const int wr   = wid >> 1;
  const int wc   = wid & 1;
  const int half = lane >> 5;
  const int l31  = lane & 31;
  const int b    = blockIdx.x & 31;
  const int pt   = blockIdx.x >> 5;
  const int row0 = pt * PT;

  const float* pfb = pf + (size_t)b * P * D;
  const float* ofb = of + (size_t)b * O * D;
  const float* ivp = invp + b * P + row0;
  const float* ivq = invp + b * P;
  const float* ivo = invo + b * O;

  float s1p[2][16];
  #pragma unroll
  for (int m = 0; m < 2; ++m)
    #pragma unroll
    for (int r = 0; r < 16; ++r) s1p[m][r] = 0.f;

  auto stage = [&](const float* __restrict__ src, const float* __restrict__ inv,
                   __hip_bfloat16* __restrict__ lds, int k0) {
    #pragma unroll
    for (int i = 0; i < 8; ++i) {
      int c = i * 256 + tid;
      int rr = c >> 4, kc = c & 15;
      float4 v = *(const float4*)(src + (size_t)rr * D + k0 + (kc << 2));
      float s = inv[rr];
      int off = rr * BK + ((((kc >> 1) ^ (rr & 7)) << 3) | ((kc & 1) << 2));
      ushort4 w;
      w.x = f2bf(v.x * s);
      w.y = f2bf(v.y * s);
      w.z = f2bf(v.z * s);
      w.w = f2bf(v.w * s);
      *reinterpret_cast<ushort4*>(lds + off) = w;
    }
  };

  for (int ct = 0; ct < 9; ++ct) {
    const float* bsrc = (ct == 0) ? ofb : pfb + (size_t)(ct - 1) * 128 * D;
    const float* binv = (ct == 0) ? ivo : ivq + (ct - 1) * 128;

    f32x16 acc[2][2];
    #pragma unroll
    for (int m = 0; m < 2; ++m)
      #pragma unroll
      for (int n = 0; n < 2; ++n)
        #pragma unroll
        for (int k = 0; k < 16; ++k) acc[m][n][k] = 0.f;

    for (int ks = 0; ks < D / BK; ++ks) {
      __syncthreads();
      stage(pfb + (size_t)row0 * D, ivp, As, ks * BK);
      stage(bsrc, binv, Bs, ks * BK);
      __syncthreads();
      #pragma unroll
      for (int kc = 0; kc < 4; ++kc) {
        short8 af[2], bfr[2];
        #pragma unroll
        for (int m = 0; m < 2; ++m) {
          int row = wr * 64 + m * 32 + l31;
          af[m] = *reinterpret_cast<const short8*>(
              As + row * BK + ((((kc << 1) | half) ^ (row & 7)) << 3));
        }
        #pragma unroll
        for (int n = 0; n < 2; ++n) {
          int col = wc * 64 + n * 32 + l31;
          bfr[n] = *reinterpret_cast<const short8*>(
              Bs + col * BK + ((((kc << 1) | half) ^ (col & 7)) << 3));
        }
        #pragma unroll
        for (int m = 0; m < 2; ++m)
          #pragma unroll
          for (int n = 0; n < 2; ++n)
            acc[m][n] = __builtin_amdgcn_mfma_f32_32x32x16_bf16(
                af[m], bfr[n], acc[m][n], 0, 0, 0);
      }
    }

    if (ct == 0) {
      #pragma unroll
      for (int m = 0; m < 2; ++m) {
        #pragma unroll
        for (int r = 0; r < 16; ++r) {
          int lrow = wr * 64 + m * 32 + (r & 3) + ((r >> 2) << 3) + (half << 2);
          size_t base = ((size_t)b * P + row0 + lrow) * O;
          float dsum = 0.f, s2s = 0.f, eis = 0.f, mval = -1e30f;
          int midx = 0;
          #pragma unroll
          for (int n = 0; n < 2; ++n) {
            int col = wc * 64 + n * 32 + l31;
            float sim = acc[m][n][r];
            float e = exp2f(sim * SCL);
            float v1 = e1i[base + col];
            float v2 = e2j[base + col];
            dsum += v1 * e;
            s2s  += v2 * e;
            eis  += v1;
            if (sim > mval) { mval = sim; midx = col; }
          }
          #pragma unroll
          for (int s = 1; s < 32; s <<= 1) {
            dsum += __shfl_xor(dsum, s);
            s2s  += __shfl_xor(s2s, s);
            eis  += __shfl_xor(eis, s);
            float ov = __shfl_xor(mval, s);
            int   oi = __shfl_xor(midx, s);
            if (ov > mval || (ov == mval && oi < midx)) { mval = ov; midx = oi; }
          }
          if (l31 == 0) {
            d_l[wc][lrow] = dsum;
            s2_l[wc][lrow] = s2s;
            ei_l[wc][lrow] = eis;
            mv_l[wc][lrow] = mval;
            mi_l[wc][lrow] = midx;
          }
        }
      }
    } else {
      const int qbase = (ct - 1) * 128;
      #pragma unroll
      for (int m = 0; m < 2; ++m) {
        #pragma unroll
        for (int r = 0; r < 16; ++r) {
          int lrow = wr * 64 + m * 32 + (r & 3) + ((r >> 2) << 3) + (half << 2);
          size_t base = ((size_t)b * P + row0 + lrow) * P + qbase;
          float s = 0.f;
          #pragma unroll
          for (int n = 0; n < 2; ++n) {
            int col = wc * 64 + n * 32 + l31;
            s += e1j[base + col] * exp2f(acc[m][n][r] * SCL);
          }
          s1p[m][r] += s;
        }
      }
    }
  }

  #pragma unroll
  for (int m = 0; m < 2; ++m) {
    #pragma unroll
    for (int r = 0; r < 16; ++r) {
      float v = s1p[m][r];
      #pragma unroll
      for (int s = 1; s < 32; s <<= 1) v += __shfl_xor(v, s);
      if (l31 == 0) {
        int lrow = wr * 64 + m * 32 + (r & 3) + ((r >> 2) << 3) + (half << 2);
        s1_l[wc][lrow] = v;
      }
    }
  }
  __syncthreads();

  float lsum = 0.f, lbl = 0.f, vct = 0.f;
  if (tid < PT) {
    float delta = d_l[0][tid] + d_l[1][tid];
    float s2 = s2_l[0][tid] + s2_l[1][tid];
    float eis = ei_l[0][tid] + ei_l[1][tid];
    float s1 = s1_l[0][tid] + s1_l[1][tid];
    float m0 = mv_l[0][tid], m1 = mv_l[1][tid];
    int mi = (m1 > m0) ? mi_l[1][tid] : mi_l[0][tid];
    float valid = (eis > 0.f) ? 1.f : 0.f;
    float ratio = delta / (delta + s1 + s2 + EPS);
    float loss = -logf(ratio + EPS);
    float label = e1i[((size_t)b * P + row0 + tid) * O + mi];
    lsum = loss * valid;
    lbl  = label * valid;
    vct  = valid;
  }
  #pragma unroll
  for (int s = 1; s < 64; s <<= 1) {
    lsum += __shfl_xor(lsum, s);
    lbl  += __shfl_xor(lbl, s);
    vct  += __shfl_xor(vct, s);
  }
  if (lane == 0) {
    red[wid * 3 + 0] = lsum;
    red[wid * 3 + 1] = lbl;
    red[wid * 3 + 2] = vct;
  }
  __syncthreads();
  if (tid == 0) {
    float a = red[0] + red[3] + red[6] + red[9];
    float c = red[1] + red[4] + red[7] + red[10];
    float v = red[2] + red[5] + red[8] + red[11];
    atomicAdd(&accum[0], a);
    atomicAdd(&accum[1], c);
    atomicAdd(&accum[2], v);
  }
}

extern "C" void kernel_launch(void* const* d_in, const int* in_sizes, int n_in,
                              void* d_out, int out_size, void* d_ws, size_t ws_size,
                              hipStream_t stream) {
  const float* pf  = (const float*)d_in[0];
  const float* of  = (const float*)d_in[1];
  const float* e1i = (const float*)d_in[2];
  const float* e1j = (const float*)d_in[3];
  const float* e2j = (const float*)d_in[4];

  char* base = (char*)d_ws;
  constexpr size_t NR = (size_t)BB * P;               // 32768 rows
  float* accum                 = (float*)base;                    // 64 B
  float* d_row                 = (float*)(base + 64);
  float* s1_row                = (float*)(base + 64 + 4 * NR);
  float* s2_row                = (float*)(base + 64 + 8 * NR);
  unsigned long long* pk_row   = (unsigned long long*)(base + 64 + 12 * NR);
  int* ip_row                  = (int*)(base + 64 + 20 * NR);
  __hip_bfloat16* pn           = (__hip_bfloat16*)(base + 64 + 24 * NR);
  const size_t pn_bytes = (size_t)BB * P * D * 2;
  const size_t on_bytes = (size_t)BB * O * D * 2;
  __hip_bfloat16* on           = (__hip_bfloat16*)(base + 64 + 24 * NR + pn_bytes);
  const size_t need = 64 + 24 * NR + pn_bytes + on_bytes;

  if (ws_size >= need) {
    hipMemsetAsync(base, 0, 64 + 20 * NR, stream);        // accum,d,s1,s2,pk
    hipMemsetAsync(ip_row, 0xFF, 4 * NR, stream);         // ip = -1
    prep_kernel<<<(BB * P + BB * O) / 4, 256, 0, stream>>>(pf, of, pn, on);
    icl_main5<<<BB * 36, 512, 0, stream>>>(pn, on, e1i, e1j, e2j,
                                           d_row, s1_row, s2_row, pk_row, ip_row);
    icl_reduce<<<NR / 256, 256, 0, stream>>>(d_row, s1_row, s2_row, pk_row,
                                             ip_row, accum);
  } else {
    float* ws   = (float*)d_ws;
    float* invp = ws + 16;
    float* invo = ws + 16 + BB * P;
    hipMemsetAsync(accum, 0, 16 * sizeof(float), stream);
    norm_kernel<<<(BB * P + BB * O) / 4, 256, 0, stream>>>(pf, of, invp, invo);
    icl_main_v1<<<BB * (P / 128), 256, 0, stream>>>(pf, of, e1i, e1j, e2j,
                                                    invp, invo, accum);
  }
  finalize_kernel<<<1, 64, 0, stream>>>(accum, (float*)d_out);
}

// Round 6
// 179.532 us; speedup vs baseline: 1.9908x; 1.0079x over previous
//
#include <hip/hip_runtime.h>
#include <hip/hip_bf16.h>

constexpr int BB = 32;     // batches
constexpr int P  = 1024;   // patches per batch
constexpr int O  = 128;    // objects per batch
constexpr int D  = 512;    // feature dim
constexpr float EPS = 1e-8f;
constexpr float SCL = 14.426950408889634f; // (1/0.1) * log2(e)

typedef __attribute__((ext_vector_type(8))) short short8;
typedef __attribute__((ext_vector_type(16))) float f32x16;

__device__ __forceinline__ unsigned short f2bf(float f) {
  __hip_bfloat16 h = __float2bfloat16(f);
  unsigned short u;
  __builtin_memcpy(&u, &h, sizeof(u));
  return u;
}

__device__ __forceinline__ void gld_lds16(const void* g, void* l) {
  __builtin_amdgcn_global_load_lds(
      (const __attribute__((address_space(1))) void*)g,
      (__attribute__((address_space(3))) void*)l, 16, 0, 0);
}

// ---------------- prep: normalized bf16 features into workspace ------------
__global__ __launch_bounds__(256) void prep_kernel(
    const float* __restrict__ pf, const float* __restrict__ of,
    __hip_bfloat16* __restrict__ pn, __hip_bfloat16* __restrict__ on) {
  int lane = threadIdx.x & 63;
  int row = blockIdx.x * 4 + (threadIdx.x >> 6);
  const float* src;
  __hip_bfloat16* dst;
  if (row < BB * P) {
    src = pf + (size_t)row * D;
    dst = pn + (size_t)row * D;
  } else {
    int r = row - BB * P;
    if (r >= BB * O) return;
    src = of + (size_t)r * D;
    dst = on + (size_t)r * D;
  }
  float4 v0 = *(const float4*)(src + lane * 8);
  float4 v1 = *(const float4*)(src + lane * 8 + 4);
  float ss = v0.x * v0.x + v0.y * v0.y + v0.z * v0.z + v0.w * v0.w +
             v1.x * v1.x + v1.y * v1.y + v1.z * v1.z + v1.w * v1.w;
  #pragma unroll
  for (int s = 1; s < 64; s <<= 1) ss += __shfl_xor(ss, s);
  float sc = 1.0f / fmaxf(sqrtf(ss), 1e-12f);
  short8 w;
  w[0] = (short)f2bf(v0.x * sc); w[1] = (short)f2bf(v0.y * sc);
  w[2] = (short)f2bf(v0.z * sc); w[3] = (short)f2bf(v0.w * sc);
  w[4] = (short)f2bf(v1.x * sc); w[5] = (short)f2bf(v1.y * sc);
  w[6] = (short)f2bf(v1.z * sc); w[7] = (short)f2bf(v1.w * sc);
  *reinterpret_cast<short8*>(dst + lane * 8) = w;
}

// ---- main v6: v5 + depth-4 A-prefetch register ring (issue-early) --------
// grid = 32 batches x 18 stripes(64 cols) x 2 row-halves = 1152 blocks.
// stripes 0,1 = objects (cols 0..127), stripes 2..17 = patches.
// block = 8 waves; per pass each wave owns 32 rows x 64 cols; 2 passes.
__global__ __launch_bounds__(512, 4) void icl_main6(
    const __hip_bfloat16* __restrict__ pn, const __hip_bfloat16* __restrict__ on,
    const float* __restrict__ e1i, const float* __restrict__ e1j,
    const float* __restrict__ e2j,
    float* __restrict__ d_row, float* __restrict__ s1_row,
    float* __restrict__ s2_row, unsigned long long* __restrict__ pk_row,
    int* __restrict__ ip_row) {

  // [kc 0..63][col 0..63] 16B chunks; chunk(kc,col) holds B[col][kc*8..+8].
  // ds_read: 32 lanes read consecutive cols -> contiguous 512B, conflict-free.
  __shared__ __hip_bfloat16 Bs[64 * 64 * 8];   // 64 KB

  const int tid  = threadIdx.x;
  const int l    = tid & 63;
  const int wid  = tid >> 6;
  const int half = l >> 5;
  const int l31  = l & 31;

  const int bid    = blockIdx.x;
  const int batch  = bid & 31;            // same-batch blocks share XCD (b%8)
  const int unit   = bid >> 5;            // 0..35
  const int stripe = unit >> 1;           // 0..17
  const int rh     = unit & 1;            // row half: rows [rh*512, rh*512+512)
  const bool isobj = stripe < 2;

  const __hip_bfloat16* pnb = pn + (size_t)batch * P * D;
  const __hip_bfloat16* onb = on + (size_t)batch * O * D;
  const __hip_bfloat16* bsrc =
      isobj ? onb + (size_t)stripe * 64 * D
            : pnb + (size_t)(stripe - 2) * 64 * D;

  // stage B once: chunk idx = kc*64 + col; dest linear in idx (gld_lds ok)
  #pragma unroll
  for (int i = 0; i < 8; ++i) {
    const int idx = i * 512 + tid;
    gld_lds16(bsrc + (size_t)(idx & 63) * D + (idx >> 6) * 8,
              (char*)Bs + (size_t)idx * 16);
  }
  __syncthreads();   // compiler drains vmcnt before barrier: Bs ready

  const int cb = stripe * 64;                   // global col base (obj space)
  const int pb = (stripe - 2) * 64;             // global col base (patch space)

  for (int p = 0; p < 2; ++p) {
    const int rowt = rh * 512 + p * 256 + wid * 32;   // wave's 32-row tile
    const __hip_bfloat16* a0 = pnb + (size_t)(rowt + l31) * D + half * 8;

    // depth-4 prefetch ring: A[s+4] issued before A[s] is consumed
    short8 ring[4];
    #pragma unroll
    for (int i = 0; i < 4; ++i)
      ring[i] = *reinterpret_cast<const short8*>(a0 + i * 16);

    f32x16 acc0, acc1;
    #pragma unroll
    for (int k = 0; k < 16; ++k) { acc0[k] = 0.f; acc1[k] = 0.f; }

    #pragma unroll
    for (int s = 0; s < 32; ++s) {
      short8 A0 = ring[s & 3];
      if (s < 28)
        ring[s & 3] = *reinterpret_cast<const short8*>(a0 + (s + 4) * 16);
      const char* bb = (const char*)Bs + (((s << 1) | half) << 10);
      short8 b0 = *reinterpret_cast<const short8*>(bb + (l31 << 4));
      short8 b1 = *reinterpret_cast<const short8*>(bb + ((32 + l31) << 4));
      acc0 = __builtin_amdgcn_mfma_f32_32x32x16_bf16(A0, b0, acc0, 0, 0, 0);
      acc1 = __builtin_amdgcn_mfma_f32_32x32x16_bf16(A0, b1, acc1, 0, 0, 0);
    }

    if (isobj) {
      #pragma unroll
      for (int r = 0; r < 16; ++r) {
        const int lrow = (r & 3) + ((r >> 2) << 3) + (half << 2);
        const size_t grow = (size_t)batch * P + rowt + lrow;
        const size_t gb = grow * O + cb;
        const int c0 = cb + l31, c1 = cb + 32 + l31;
        float s0 = acc0[r], s1v = acc1[r];
        float e0 = exp2f(s0 * SCL), e1 = exp2f(s1v * SCL);
        float m10 = e1i[gb + l31], m11 = e1i[gb + 32 + l31];
        float m20 = e2j[gb + l31], m21 = e2j[gb + 32 + l31];
        float dv  = m10 * e0 + m11 * e1;
        float s2v = m20 * e0 + m21 * e1;
        int ipv = (m11 > 0.5f) ? c1 : ((m10 > 0.5f) ? c0 : -1);
        float mvv; int miv;
        if (s1v > s0) { mvv = s1v; miv = c1; } else { mvv = s0; miv = c0; }
        #pragma unroll
        for (int s = 1; s < 32; s <<= 1) {
          dv  += __shfl_xor(dv, s);
          s2v += __shfl_xor(s2v, s);
          ipv  = max(ipv, __shfl_xor(ipv, s));
          float ov = __shfl_xor(mvv, s);
          int   oi = __shfl_xor(miv, s);
          if (ov > mvv || (ov == mvv && oi < miv)) { mvv = ov; miv = oi; }
        }
        if (l31 == 0) {
          if (dv != 0.f) atomicAdd(&d_row[grow], dv);
          atomicAdd(&s2_row[grow], s2v);
          unsigned long long pkv =
              ((unsigned long long)__float_as_uint(mvv + 2.0f) << 32) |
              (unsigned)(0xFFFFFFFFu - (unsigned)miv);
          atomicMax(&pk_row[grow], pkv);
          if (ipv >= 0) atomicMax(&ip_row[grow], ipv);
        }
      }
    } else {
      #pragma unroll
      for (int r = 0; r < 16; ++r) {
        const int lrow = (r & 3) + ((r >> 2) << 3) + (half << 2);
        const size_t grow = (size_t)batch * P + rowt + lrow;
        const size_t gb = grow * P + pb;
        float v = e1j[gb + l31] * exp2f(acc0[r] * SCL) +
                  e1j[gb + 32 + l31] * exp2f(acc1[r] * SCL);
        #pragma unroll
        for (int s = 1; s < 32; s <<= 1) v += __shfl_xor(v, s);
        if (l31 == 0) atomicAdd(&s1_row[grow], v);
      }
    }
  }
}

// ---------------- per-row loss + scalar reduction --------------------------
__global__ __launch_bounds__(256) void icl_reduce(
    const float* __restrict__ d_row, const float* __restrict__ s1_row,
    const float* __restrict__ s2_row, const unsigned long long* __restrict__ pk_row,
    const int* __restrict__ ip_row, float* __restrict__ accum) {
  __shared__ float red[12];
  const int tid = threadIdx.x;
  const int row = blockIdx.x * 256 + tid;
  float d = d_row[row], a = s1_row[row], c = s2_row[row];
  int ipv = ip_row[row];
  int miv = (int)(0xFFFFFFFFu - (unsigned)(pk_row[row] & 0xFFFFFFFFull));
  float valid = (ipv >= 0) ? 1.f : 0.f;
  float ratio = d / (d + a + c + EPS);
  float lsum = -logf(ratio + EPS) * valid;
  float lbl  = (ipv >= 0 && miv == ipv) ? 1.f : 0.f;
  float vct  = valid;
  #pragma unroll
  for (int s = 1; s < 64; s <<= 1) {
    lsum += __shfl_xor(lsum, s);
    lbl  += __shfl_xor(lbl, s);
    vct  += __shfl_xor(vct, s);
  }
  const int wid = tid >> 6;
  if ((tid & 63) == 0) {
    red[wid * 3 + 0] = lsum;
    red[wid * 3 + 1] = lbl;
    red[wid * 3 + 2] = vct;
  }
  __syncthreads();
  if (tid == 0) {
    atomicAdd(&accum[0], red[0] + red[3] + red[6] + red[9]);
    atomicAdd(&accum[1], red[1] + red[4] + red[7] + red[10]);
    atomicAdd(&accum[2], red[2] + red[5] + red[8] + red[11]);
  }
}

__global__ void finalize_kernel(const float* __restrict__ accum,
                                float* __restrict__ out) {
  if (threadIdx.x == 0 && blockIdx.x == 0) {
    float nv = accum[2];
    out[0] = accum[0] / nv;
    out[1] = accum[1] / nv;
  }
}

// ---------------- fallback path (round-1, known correct) -------------------
__global__ __launch_bounds__(256) void norm_kernel(
    const float* __restrict__ pf, const float* __restrict__ of,
    float* __restrict__ invp, float* __restrict__ invo) {
  int lane = threadIdx.x & 63;
  int row = blockIdx.x * 4 + (threadIdx.x >> 6);
  const float* src;
  float* dst;
  if (row < BB * P) {
    src = pf + (size_t)row * D;
    dst = invp + row;
  } else {
    int r = row - BB * P;
    if (r >= BB * O) return;
    src = of + (size_t)r * D;
    dst = invo + r;
  }
  float ss = 0.f;
  #pragma unroll
  for (int i = 0; i < 2; ++i) {
    float4 v = *(const float4*)(src + (lane + 64 * i) * 4);
    ss += v.x * v.x + v.y * v.y + v.z * v.z + v.w * v.w;
  }
  #pragma unroll
  for (int s = 1; s < 64; s <<= 1) ss += __shfl_xor(ss, s);
  if (lane == 0) *dst = 1.0f / fmaxf(sqrtf(ss), 1e-12f);
}

__global__ __launch_bounds__(256) void icl_main_v1(
    const float* __restrict__ pf, const float* __restrict__ of,
    const float* __restrict__ e1i, const float* __restrict__ e1j,
    const float* __restrict__ e2j, const float* __restrict__ invp,
    const float* __restrict__ invo, float* __restrict__ accum) {
  constexpr int PT = 128, BK = 64;
  __shared__ __hip_bfloat16 As[PT * BK];
  __shared__ __hip_bfloat16 Bs[PT * BK];
  __shared__ float d_l[2][PT], s2_l[2][PT], ei_l[2][PT], s1_l[2][PT], mv_l[2][PT];
  __shared__ int   mi_l[2][PT];
  __shared__ float red[12];

  const int tid  = threadIdx.x;
  const int lane = tid & 63;
  const int wid  = tid >> 6;
  const int wr   = wid >> 1;
  const int wc   = wid & 1;
  const int half = lane >> 5;
  const int l31  = lane & 31;
  const int b    = blockIdx.x & 31;
  const int pt   = blockIdx.x >> 5;
  const int row0 = pt * PT;

  const float* pfb = pf + (size_t)b * P * D;
  const float* ofb = of + (size_t)b * O * D;
  const float* ivp = invp + b * P + row0;
  const float* ivq = invp + b * P;
  const float* ivo = invo + b * O;

  float s1p[2][16];
  #pragma unroll
  for (int m = 0; m < 2; ++m)
    #pragma unroll
    for (int r = 0; r < 16; ++r) s1p[m][r] = 0.f;

  auto stage = [&](const float* __restrict__ src, const float* __restrict__ inv,
                   __hip_bfloat16* __restrict__ lds, int k0) {
    #pragma unroll
    for (int i = 0; i < 8; ++i) {
      int c = i * 256 + tid;
      int rr = c >> 4, kc = c & 15;
      float4 v = *(const float4*)(src + (size_t)rr * D + k0 + (kc << 2));
      float s = inv[rr];
      int off = rr * BK + ((((kc >> 1) ^ (rr & 7)) << 3) | ((kc & 1) << 2));
      ushort4 w;
      w.x = f2bf(v.x * s);
      w.y = f2bf(v.y * s);
      w.z = f2bf(v.z * s);
      w.w = f2bf(v.w * s);
      *reinterpret_cast<ushort4*>(lds + off) = w;
    }
  };

  for (int ct = 0; ct < 9; ++ct) {
    const float* bsrc = (ct == 0) ? ofb : pfb + (size_t)(ct - 1) * 128 * D;
    const float* binv = (ct == 0) ? ivo : ivq + (ct - 1) * 128;

    f32x16 acc[2][2];
    #pragma unroll
    for (int m = 0; m < 2; ++m)
      #pragma unroll
      for (int n = 0; n < 2; ++n)
        #pragma unroll
        for (int k = 0; k < 16; ++k) acc[m][n][k] = 0.f;

    for (int ks = 0; ks < D / BK; ++ks) {
      __syncthreads();
      stage(pfb + (size_t)row0 * D, ivp, As, ks * BK);
      stage(bsrc, binv, Bs, ks * BK);
      __syncthreads();
      #pragma unroll
      for (int kc = 0; kc < 4; ++kc) {
        short8 af[2], bfr[2];
        #pragma unroll
        for (int m = 0; m < 2; ++m) {
          int row = wr * 64 + m * 32 + l31;
          af[m] = *reinterpret_cast<const short8*>(
              As + row * BK + ((((kc << 1) | half) ^ (row & 7)) << 3));
        }
        #pragma unroll
        for (int n = 0; n < 2; ++n) {
          int col = wc * 64 + n * 32 + l31;
          bfr[n] = *reinterpret_cast<const short8*>(
              Bs + col * BK + ((((kc << 1) | half) ^ (col & 7)) << 3));
        }
        #pragma unroll
        for (int m = 0; m < 2; ++m)
          #pragma unroll
          for (int n = 0; n < 2; ++n)
            acc[m][n] = __builtin_amdgcn_mfma_f32_32x32x16_bf16(
                af[m], bfr[n], acc[m][n], 0, 0, 0);
      }
    }

    if (ct == 0) {
      #pragma unroll
      for (int m = 0; m < 2; ++m) {
        #pragma unroll
        for (int r = 0; r < 16; ++r) {
          int lrow = wr * 64 + m * 32 + (r & 3) + ((r >> 2) << 3) + (half << 2);
          size_t base = ((size_t)b * P + row0 + lrow) * O;
          float dsum = 0.f, s2s = 0.f, eis = 0.f, mval = -1e30f;
          int midx = 0;
          #pragma unroll
          for (int n = 0; n < 2; ++n) {
            int col = wc * 64 + n * 32 + l31;
            float sim = acc[m][n][r];
            float e = exp2f(sim * SCL);
            float v1 = e1i[base + col];
            float v2 = e2j[base + col];
            dsum += v1 * e;
            s2s  += v2 * e;
            eis  += v1;
            if (sim > mval) { mval = sim; midx = col; }
          }
          #pragma unroll
          for (int s = 1; s < 32; s <<= 1) {
            dsum += __shfl_xor(dsum, s);
            s2s  += __shfl_xor(s2s, s);
            eis  += __shfl_xor(eis, s);
            float ov = __shfl_xor(mval, s);
            int   oi = __shfl_xor(midx, s);
            if (ov > mval || (ov == mval && oi < midx)) { mval = ov; midx = oi; }
          }
          if (l31 == 0) {
            d_l[wc][lrow] = dsum;
            s2_l[wc][lrow] = s2s;
            ei_l[wc][lrow] = eis;
            mv_l[wc][lrow] = mval;
            mi_l[wc][lrow] = midx;
          }
        }
      }
    } else {
      const int qbase = (ct - 1) * 128;
      #pragma unroll
      for (int m = 0; m < 2; ++m) {
        #pragma unroll
        for (int r = 0; r < 16; ++r) {
          int lrow = wr * 64 + m * 32 + (r & 3) + ((r >> 2) << 3) + (half << 2);
          size_t base = ((size_t)b * P + row0 + lrow) * P + qbase;
          float s = 0.f;
          #pragma unroll
          for (int n = 0; n < 2; ++n) {
            int col = wc * 64 + n * 32 + l31;
            s += e1j[base + col] * exp2f(acc[m][n][r] * SCL);
          }
          s1p[m][r] += s;
        }
      }
    }
  }

  #pragma unroll
  for (int m = 0; m < 2; ++m) {
    #pragma unroll
    for (int r = 0; r < 16; ++r) {
      float v = s1p[m][r];
      #pragma unroll
      for (int s = 1; s < 32; s <<= 1) v += __shfl_xor(v, s);
      if (l31 == 0) {
        int lrow = wr * 64 + m * 32 + (r & 3) + ((r >> 2) << 3) + (half << 2);
        s1_l[wc][lrow] = v;
      }
    }
  }
  __syncthreads();

  float lsum = 0.f, lbl = 0.f, vct = 0.f;
  if (tid < PT) {
    float delta = d_l[0][tid] + d_l[1][tid];
    float s2 = s2_l[0][tid] + s2_l[1][tid];
    float eis = ei_l[0][tid] + ei_l[1][tid];
    float s1 = s1_l[0][tid] + s1_l[1][tid];
    float m0 = mv_l[0][tid], m1 = mv_l[1][tid];
    int mi = (m1 > m0) ? mi_l[1][tid] : mi_l[0][tid];
    float valid = (eis > 0.f) ? 1.f : 0.f;
    float ratio = delta / (delta + s1 + s2 + EPS);
    float loss = -logf(ratio + EPS);
    float label = e1i[((size_t)b * P + row0 + tid) * O + mi];
    lsum = loss * valid;
    lbl  = label * valid;
    vct  = valid;
  }
  #pragma unroll
  for (int s = 1; s < 64; s <<= 1) {
    lsum += __shfl_xor(lsum, s);
    lbl  += __shfl_xor(lbl, s);
    vct  += __shfl_xor(vct, s);
  }
  if (lane == 0) {
    red[wid * 3 + 0] = lsum;
    red[wid * 3 + 1] = lbl;
    red[wid * 3 + 2] = vct;
  }
  __syncthreads();
  if (tid == 0) {
    float a = red[0] + red[3] + red[6] + red[9];
    float c = red[1] + red[4] + red[7] + red[10];
    float v = red[2] + red[5] + red[8] + red[11];
    atomicAdd(&accum[0], a);
    atomicAdd(&accum[1], c);
    atomicAdd(&accum[2], v);
  }
}

extern "C" void kernel_launch(void* const* d_in, const int* in_sizes, int n_in,
                              void* d_out, int out_size, void* d_ws, size_t ws_size,
                              hipStream_t stream) {
  const float* pf  = (const float*)d_in[0];
  const float* of  = (const float*)d_in[1];
  const float* e1i = (const float*)d_in[2];
  const float* e1j = (const float*)d_in[3];
  const float* e2j = (const float*)d_in[4];

  char* base = (char*)d_ws;
  constexpr size_t NR = (size_t)BB * P;               // 32768 rows
  float* accum                 = (float*)base;                    // 64 B
  float* d_row                 = (float*)(base + 64);
  float* s1_row                = (float*)(base + 64 + 4 * NR);
  float* s2_row                = (float*)(base + 64 + 8 * NR);
  unsigned long long* pk_row   = (unsigned long long*)(base + 64 + 12 * NR);
  int* ip_row                  = (int*)(base + 64 + 20 * NR);
  __hip_bfloat16* pn           = (__hip_bfloat16*)(base + 64 + 24 * NR);
  const size_t pn_bytes = (size_t)BB * P * D * 2;
  const size_t on_bytes = (size_t)BB * O * D * 2;
  __hip_bfloat16* on           = (__hip_bfloat16*)(base + 64 + 24 * NR + pn_bytes);
  const size_t need = 64 + 24 * NR + pn_bytes + on_bytes;

  if (ws_size >= need) {
    hipMemsetAsync(base, 0, 64 + 20 * NR, stream);        // accum,d,s1,s2,pk
    hipMemsetAsync(ip_row, 0xFF, 4 * NR, stream);         // ip = -1
    prep_kernel<<<(BB * P + BB * O) / 4, 256, 0, stream>>>(pf, of, pn, on);
    icl_main6<<<BB * 36, 512, 0, stream>>>(pn, on, e1i, e1j, e2j,
                                           d_row, s1_row, s2_row, pk_row, ip_row);
    icl_reduce<<<NR / 256, 256, 0, stream>>>(d_row, s1_row, s2_row, pk_row,
                                             ip_row, accum);
  } else {
    float* ws   = (float*)d_ws;
    float* invp = ws + 16;
    float* invo = ws + 16 + BB * P;
    hipMemsetAsync(accum, 0, 16 * sizeof(float), stream);
    norm_kernel<<<(BB * P + BB * O) / 4, 256, 0, stream>>>(pf, of, invp, invo);
    icl_main_v1<<<BB * (P / 128), 256, 0, stream>>>(pf, of, e1i, e1j, e2j,
                                                    invp, invo, accum);
  }
  finalize_kernel<<<1, 64, 0, stream>>>(accum, (float*)d_out);
}

// Round 7
// 151.027 us; speedup vs baseline: 2.3665x; 1.1887x over previous
//
#include <hip/hip_runtime.h>
#include <hip/hip_bf16.h>

constexpr int BB = 32;     // batches
constexpr int P  = 1024;   // patches per batch
constexpr int O  = 128;    // objects per batch
constexpr int D  = 512;    // feature dim
constexpr float EPS = 1e-8f;
constexpr float SCL = 14.426950408889634f; // (1/0.1) * log2(e)

typedef __attribute__((ext_vector_type(8))) short short8;
typedef __attribute__((ext_vector_type(16))) float f32x16;

__device__ __forceinline__ unsigned short f2bf(float f) {
  __hip_bfloat16 h = __float2bfloat16(f);
  unsigned short u;
  __builtin_memcpy(&u, &h, sizeof(u));
  return u;
}

__device__ __forceinline__ void gld_lds16(const void* g, void* l) {
  __builtin_amdgcn_global_load_lds(
      (const __attribute__((address_space(1))) void*)g,
      (__attribute__((address_space(3))) void*)l, 16, 0, 0);
}

// ---------------- prep: normalized bf16 features into workspace ------------
__global__ __launch_bounds__(256) void prep_kernel(
    const float* __restrict__ pf, const float* __restrict__ of,
    __hip_bfloat16* __restrict__ pn, __hip_bfloat16* __restrict__ on) {
  int lane = threadIdx.x & 63;
  int row = blockIdx.x * 4 + (threadIdx.x >> 6);
  const float* src;
  __hip_bfloat16* dst;
  if (row < BB * P) {
    src = pf + (size_t)row * D;
    dst = pn + (size_t)row * D;
  } else {
    int r = row - BB * P;
    if (r >= BB * O) return;
    src = of + (size_t)r * D;
    dst = on + (size_t)r * D;
  }
  float4 v0 = *(const float4*)(src + lane * 8);
  float4 v1 = *(const float4*)(src + lane * 8 + 4);
  float ss = v0.x * v0.x + v0.y * v0.y + v0.z * v0.z + v0.w * v0.w +
             v1.x * v1.x + v1.y * v1.y + v1.z * v1.z + v1.w * v1.w;
  #pragma unroll
  for (int s = 1; s < 64; s <<= 1) ss += __shfl_xor(ss, s);
  float sc = 1.0f / fmaxf(sqrtf(ss), 1e-12f);
  short8 w;
  w[0] = (short)f2bf(v0.x * sc); w[1] = (short)f2bf(v0.y * sc);
  w[2] = (short)f2bf(v0.z * sc); w[3] = (short)f2bf(v0.w * sc);
  w[4] = (short)f2bf(v1.x * sc); w[5] = (short)f2bf(v1.y * sc);
  w[6] = (short)f2bf(v1.z * sc); w[7] = (short)f2bf(v1.w * sc);
  *reinterpret_cast<short8*>(dst + lane * 8) = w;
}

// ---- main v7: m97 template. 128x128 tile, BK=64, gld_lds16 staging, ------
// 4 waves (each 64x64 = acc[2][2] of 32x32), 2 barriers/K-step, 3 blocks/CU.
// grid = 32 batches x 8 rowtiles x 9 coltiles (ct 0 = objects).
__global__ __launch_bounds__(256, 3) void icl_main7(
    const __hip_bfloat16* __restrict__ pn, const __hip_bfloat16* __restrict__ on,
    const float* __restrict__ e1i, const float* __restrict__ e1j,
    const float* __restrict__ e2j,
    float* __restrict__ d_row, float* __restrict__ s1_row,
    float* __restrict__ s2_row, unsigned long long* __restrict__ pk_row,
    int* __restrict__ ip_row) {

  // XOR-swizzled (pre-swizzled global source): 16B chunk c of row r at c^(r&7)
  __shared__ __hip_bfloat16 As[128 * 64];   // 16 KB
  __shared__ __hip_bfloat16 Bs[128 * 64];   // 16 KB

  const int tid  = threadIdx.x;
  const int l    = tid & 63;
  const int wid  = tid >> 6;
  const int wr   = wid >> 1;    // row-group: rows wr*64..+63
  const int wc   = wid & 1;     // col-group: cols wc*64..+63
  const int half = l >> 5;
  const int l31  = l & 31;

  const int bid   = blockIdx.x;
  const int batch = bid & 31;          // same-batch blocks -> same XCD (b%8)
  const int unit  = bid >> 5;          // 0..71
  const int rt    = unit & 7;          // 8 row tiles
  const int ct    = unit >> 3;         // 9 col tiles (0 = objects)
  const int row0  = rt * 128;

  const __hip_bfloat16* pnb = pn + (size_t)batch * P * D;
  const __hip_bfloat16* onb = on + (size_t)batch * O * D;
  const __hip_bfloat16* asrc = pnb + (size_t)row0 * D;
  const __hip_bfloat16* bsrc = (ct == 0) ? onb : pnb + (size_t)(ct - 1) * 128 * D;

  // stage one 128x64 bf16 tile (1024 16B chunks) via global_load_lds:
  // dest linear (chunk q at byte q*16), source pre-swizzled: gc = c ^ (r&7)
  auto stage = [&](const __hip_bfloat16* __restrict__ src,
                   __hip_bfloat16* __restrict__ lds, int k0) {
    #pragma unroll
    for (int i = 0; i < 4; ++i) {
      int q = i * 256 + tid;
      int rr = q >> 3, c = q & 7;
      int gc = c ^ (rr & 7);
      gld_lds16(src + (size_t)rr * D + k0 + (gc << 3),
                (char*)lds + (size_t)(i * 256 + wid * 64) * 16);
    }
  };

  f32x16 acc[2][2];
  #pragma unroll
  for (int m = 0; m < 2; ++m)
    #pragma unroll
    for (int n = 0; n < 2; ++n)
      #pragma unroll
      for (int k = 0; k < 16; ++k) acc[m][n][k] = 0.f;

  for (int ks = 0; ks < 8; ++ks) {
    __syncthreads();                 // previous step's LDS reads done
    stage(asrc, As, ks * 64);
    stage(bsrc, Bs, ks * 64);
    __syncthreads();                 // staged tiles visible (vmcnt drained)
    #pragma unroll
    for (int kc = 0; kc < 4; ++kc) {
      const int ch = (kc << 1) | half;
      short8 af[2], bfr[2];
      #pragma unroll
      for (int m = 0; m < 2; ++m) {
        int row = wr * 64 + m * 32 + l31;
        af[m] = *reinterpret_cast<const short8*>(
            As + row * 64 + ((ch ^ (row & 7)) << 3));
      }
      #pragma unroll
      for (int n = 0; n < 2; ++n) {
        int col = wc * 64 + n * 32 + l31;
        bfr[n] = *reinterpret_cast<const short8*>(
            Bs + col * 64 + ((ch ^ (col & 7)) << 3));
      }
      #pragma unroll
      for (int m = 0; m < 2; ++m)
        #pragma unroll
        for (int n = 0; n < 2; ++n)
          acc[m][n] = __builtin_amdgcn_mfma_f32_32x32x16_bf16(
              af[m], bfr[n], acc[m][n], 0, 0, 0);
    }
  }

  // ---- epilogue: masked row-sums + argmax, atomic combine across blocks ---
  if (ct == 0) {
    #pragma unroll
    for (int m = 0; m < 2; ++m) {
      #pragma unroll
      for (int r = 0; r < 16; ++r) {
        const int lrow = wr * 64 + m * 32 + (r & 3) + ((r >> 2) << 3) + (half << 2);
        const size_t grow = (size_t)batch * P + row0 + lrow;
        const size_t gb = grow * O;
        const int c0 = wc * 64 + l31, c1 = wc * 64 + 32 + l31;
        float s0 = acc[m][0][r], s1v = acc[m][1][r];
        float e0 = exp2f(s0 * SCL), e1 = exp2f(s1v * SCL);
        float m10 = e1i[gb + c0], m11 = e1i[gb + c1];
        float m20 = e2j[gb + c0], m21 = e2j[gb + c1];
        float dv  = m10 * e0 + m11 * e1;
        float s2v = m20 * e0 + m21 * e1;
        int ipv = (m11 > 0.5f) ? c1 : ((m10 > 0.5f) ? c0 : -1);
        float mvv; int miv;
        if (s1v > s0) { mvv = s1v; miv = c1; } else { mvv = s0; miv = c0; }
        #pragma unroll
        for (int s = 1; s < 32; s <<= 1) {
          dv  += __shfl_xor(dv, s);
          s2v += __shfl_xor(s2v, s);
          ipv  = max(ipv, __shfl_xor(ipv, s));
          float ov = __shfl_xor(mvv, s);
          int   oi = __shfl_xor(miv, s);
          if (ov > mvv || (ov == mvv && oi < miv)) { mvv = ov; miv = oi; }
        }
        if (l31 == 0) {
          if (dv != 0.f) atomicAdd(&d_row[grow], dv);
          atomicAdd(&s2_row[grow], s2v);
          unsigned long long pkv =
              ((unsigned long long)__float_as_uint(mvv + 2.0f) << 32) |
              (unsigned)(0xFFFFFFFFu - (unsigned)miv);
          atomicMax(&pk_row[grow], pkv);
          if (ipv >= 0) atomicMax(&ip_row[grow], ipv);
        }
      }
    }
  } else {
    const int pb = (ct - 1) * 128;
    #pragma unroll
    for (int m = 0; m < 2; ++m) {
      #pragma unroll
      for (int r = 0; r < 16; ++r) {
        const int lrow = wr * 64 + m * 32 + (r & 3) + ((r >> 2) << 3) + (half << 2);
        const size_t grow = (size_t)batch * P + row0 + lrow;
        const size_t gb = grow * P + pb;
        const int c0 = wc * 64 + l31, c1 = wc * 64 + 32 + l31;
        float v = e1j[gb + c0] * exp2f(acc[m][0][r] * SCL) +
                  e1j[gb + c1] * exp2f(acc[m][1][r] * SCL);
        #pragma unroll
        for (int s = 1; s < 32; s <<= 1) v += __shfl_xor(v, s);
        if (l31 == 0) atomicAdd(&s1_row[grow], v);
      }
    }
  }
}

// ---------------- per-row loss + scalar reduction --------------------------
__global__ __launch_bounds__(256) void icl_reduce(
    const float* __restrict__ d_row, const float* __restrict__ s1_row,
    const float* __restrict__ s2_row, const unsigned long long* __restrict__ pk_row,
    const int* __restrict__ ip_row, float* __restrict__ accum) {
  __shared__ float red[12];
  const int tid = threadIdx.x;
  const int row = blockIdx.x * 256 + tid;
  float d = d_row[row], a = s1_row[row], c = s2_row[row];
  int ipv = ip_row[row];
  int miv = (int)(0xFFFFFFFFu - (unsigned)(pk_row[row] & 0xFFFFFFFFull));
  float valid = (ipv >= 0) ? 1.f : 0.f;
  float ratio = d / (d + a + c + EPS);
  float lsum = -logf(ratio + EPS) * valid;
  float lbl  = (ipv >= 0 && miv == ipv) ? 1.f : 0.f;
  float vct  = valid;
  #pragma unroll
  for (int s = 1; s < 64; s <<= 1) {
    lsum += __shfl_xor(lsum, s);
    lbl  += __shfl_xor(lbl, s);
    vct  += __shfl_xor(vct, s);
  }
  const int wid = tid >> 6;
  if ((tid & 63) == 0) {
    red[wid * 3 + 0] = lsum;
    red[wid * 3 + 1] = lbl;
    red[wid * 3 + 2] = vct;
  }
  __syncthreads();
  if (tid == 0) {
    atomicAdd(&accum[0], red[0] + red[3] + red[6] + red[9]);
    atomicAdd(&accum[1], red[1] + red[4] + red[7] + red[10]);
    atomicAdd(&accum[2], red[2] + red[5] + red[8] + red[11]);
  }
}

__global__ void finalize_kernel(const float* __restrict__ accum,
                                float* __restrict__ out) {
  if (threadIdx.x == 0 && blockIdx.x == 0) {
    float nv = accum[2];
    out[0] = accum[0] / nv;
    out[1] = accum[1] / nv;
  }
}

// ---------------- fallback path (round-1, known correct) -------------------
__global__ __launch_bounds__(256) void norm_kernel(
    const float* __restrict__ pf, const float* __restrict__ of,
    float* __restrict__ invp, float* __restrict__ invo) {
  int lane = threadIdx.x & 63;
  int row = blockIdx.x * 4 + (threadIdx.x >> 6);
  const float* src;
  float* dst;
  if (row < BB * P) {
    src = pf + (size_t)row * D;
    dst = invp + row;
  } else {
    int r = row - BB * P;
    if (r >= BB * O) return;
    src = of + (size_t)r * D;
    dst = invo + r;
  }
  float ss = 0.f;
  #pragma unroll
  for (int i = 0; i < 2; ++i) {
    float4 v = *(const float4*)(src + (lane + 64 * i) * 4);
    ss += v.x * v.x + v.y * v.y + v.z * v.z + v.w * v.w;
  }
  #pragma unroll
  for (int s = 1; s < 64; s <<= 1) ss += __shfl_xor(ss, s);
  if (lane == 0) *dst = 1.0f / fmaxf(sqrtf(ss), 1e-12f);
}

__global__ __launch_bounds__(256) void icl_main_v1(
    const float* __restrict__ pf, const float* __restrict__ of,
    const float* __restrict__ e1i, const float* __restrict__ e1j,
    const float* __restrict__ e2j, const float* __restrict__ invp,
    const float* __restrict__ invo, float* __restrict__ accum) {
  constexpr int PT = 128, BK = 64;
  __shared__ __hip_bfloat16 As[PT * BK];
  __shared__ __hip_bfloat16 Bs[PT * BK];
  __shared__ float d_l[2][PT], s2_l[2][PT], ei_l[2][PT], s1_l[2][PT], mv_l[2][PT];
  __shared__ int   mi_l[2][PT];
  __shared__ float red[12];

  const int tid  = threadIdx.x;
  const int lane = tid & 63;
  const int wid  = tid >> 6;
  const int wr   = wid >> 1;
  const int wc   = wid & 1;
  const int half = lane >> 5;
  const int l31  = lane & 31;
  const int b    = blockIdx.x & 31;
  const int pt   = blockIdx.x >> 5;
  const int row0 = pt * PT;

  const float* pfb = pf + (size_t)b * P * D;
  const float* ofb = of + (size_t)b * O * D;
  const float* ivp = invp + b * P + row0;
  const float* ivq = invp + b * P;
  const float* ivo = invo + b * O;

  float s1p[2][16];
  #pragma unroll
  for (int m = 0; m < 2; ++m)
    #pragma unroll
    for (int r = 0; r < 16; ++r) s1p[m][r] = 0.f;

  auto stage = [&](const float* __restrict__ src, const float* __restrict__ inv,
                   __hip_bfloat16* __restrict__ lds, int k0) {
    #pragma unroll
    for (int i = 0; i < 8; ++i) {
      int c = i * 256 + tid;
      int rr = c >> 4, kc = c & 15;
      float4 v = *(const float4*)(src + (size_t)rr * D + k0 + (kc << 2));
      float s = inv[rr];
      int off = rr * BK + ((((kc >> 1) ^ (rr & 7)) << 3) | ((kc & 1) << 2));
      ushort4 w;
      w.x = f2bf(v.x * s);
      w.y = f2bf(v.y * s);
      w.z = f2bf(v.z * s);
      w.w = f2bf(v.w * s);
      *reinterpret_cast<ushort4*>(lds + off) = w;
    }
  };

  for (int ct = 0; ct < 9; ++ct) {
    const float* bsrc = (ct == 0) ? ofb : pfb + (size_t)(ct - 1) * 128 * D;
    const float* binv = (ct == 0) ? ivo : ivq + (ct - 1) * 128;

    f32x16 acc[2][2];
    #pragma unroll
    for (int m = 0; m < 2; ++m)
      #pragma unroll
      for (int n = 0; n < 2; ++n)
        #pragma unroll
        for (int k = 0; k < 16; ++k) acc[m][n][k] = 0.f;

    for (int ks = 0; ks < D / BK; ++ks) {
      __syncthreads();
      stage(pfb + (size_t)row0 * D, ivp, As, ks * BK);
      stage(bsrc, binv, Bs, ks * BK);
      __syncthreads();
      #pragma unroll
      for (int kc = 0; kc < 4; ++kc) {
        short8 af[2], bfr[2];
        #pragma unroll
        for (int m = 0; m < 2; ++m) {
          int row = wr * 64 + m * 32 + l31;
          af[m] = *reinterpret_cast<const short8*>(
              As + row * BK + ((((kc << 1) | half) ^ (row & 7)) << 3));
        }
        #pragma unroll
        for (int n = 0; n < 2; ++n) {
          int col = wc * 64 + n * 32 + l31;
          bfr[n] = *reinterpret_cast<const short8*>(
              Bs + col * BK + ((((kc << 1) | half) ^ (col & 7)) << 3));
        }
        #pragma unroll
        for (int m = 0; m < 2; ++m)
          #pragma unroll
          for (int n = 0; n < 2; ++n)
            acc[m][n] = __builtin_amdgcn_mfma_f32_32x32x16_bf16(
                af[m], bfr[n], acc[m][n], 0, 0, 0);
      }
    }

    if (ct == 0) {
      #pragma unroll
      for (int m = 0; m < 2; ++m) {
        #pragma unroll
        for (int r = 0; r < 16; ++r) {
          int lrow = wr * 64 + m * 32 + (r & 3) + ((r >> 2) << 3) + (half << 2);
          size_t base = ((size_t)b * P + row0 + lrow) * O;
          float dsum = 0.f, s2s = 0.f, eis = 0.f, mval = -1e30f;
          int midx = 0;
          #pragma unroll
          for (int n = 0; n < 2; ++n) {
            int col = wc * 64 + n * 32 + l31;
            float sim = acc[m][n][r];
            float e = exp2f(sim * SCL);
            float v1 = e1i[base + col];
            float v2 = e2j[base + col];
            dsum += v1 * e;
            s2s  += v2 * e;
            eis  += v1;
            if (sim > mval) { mval = sim; midx = col; }
          }
          #pragma unroll
          for (int s = 1; s < 32; s <<= 1) {
            dsum += __shfl_xor(dsum, s);
            s2s  += __shfl_xor(s2s, s);
            eis  += __shfl_xor(eis, s);
            float ov = __shfl_xor(mval, s);
            int   oi = __shfl_xor(midx, s);
            if (ov > mval || (ov == mval && oi < midx)) { mval = ov; midx = oi; }
          }
          if (l31 == 0) {
            d_l[wc][lrow] = dsum;
            s2_l[wc][lrow] = s2s;
            ei_l[wc][lrow] = eis;
            mv_l[wc][lrow] = mval;
            mi_l[wc][lrow] = midx;
          }
        }
      }
    } else {
      const int qbase = (ct - 1) * 128;
      #pragma unroll
      for (int m = 0; m < 2; ++m) {
        #pragma unroll
        for (int r = 0; r < 16; ++r) {
          int lrow = wr * 64 + m * 32 + (r & 3) + ((r >> 2) << 3) + (half << 2);
          size_t base = ((size_t)b * P + row0 + lrow) * P + qbase;
          float s = 0.f;
          #pragma unroll
          for (int n = 0; n < 2; ++n) {
            int col = wc * 64 + n * 32 + l31;
            s += e1j[base + col] * exp2f(acc[m][n][r] * SCL);
          }
          s1p[m][r] += s;
        }
      }
    }
  }

  #pragma unroll
  for (int m = 0; m < 2; ++m) {
    #pragma unroll
    for (int r = 0; r < 16; ++r) {
      float v = s1p[m][r];
      #pragma unroll
      for (int s = 1; s < 32; s <<= 1) v += __shfl_xor(v, s);
      if (l31 == 0) {
        int lrow = wr * 64 + m * 32 + (r & 3) + ((r >> 2) << 3) + (half << 2);
        s1_l[wc][lrow] = v;
      }
    }
  }
  __syncthreads();

  float lsum = 0.f, lbl = 0.f, vct = 0.f;
  if (tid < PT) {
    float delta = d_l[0][tid] + d_l[1][tid];
    float s2 = s2_l[0][tid] + s2_l[1][tid];
    float eis = ei_l[0][tid] + ei_l[1][tid];
    float s1 = s1_l[0][tid] + s1_l[1][tid];
    float m0 = mv_l[0][tid], m1 = mv_l[1][tid];
    int mi = (m1 > m0) ? mi_l[1][tid] : mi_l[0][tid];
    float valid = (eis > 0.f) ? 1.f : 0.f;
    float ratio = delta / (delta + s1 + s2 + EPS);
    float loss = -logf(ratio + EPS);
    float label = e1i[((size_t)b * P + row0 + tid) * O + mi];
    lsum = loss * valid;
    lbl  = label * valid;
    vct  = valid;
  }
  #pragma unroll
  for (int s = 1; s < 64; s <<= 1) {
    lsum += __shfl_xor(lsum, s);
    lbl  += __shfl_xor(lbl, s);
    vct  += __shfl_xor(vct, s);
  }
  if (lane == 0) {
    red[wid * 3 + 0] = lsum;
    red[wid * 3 + 1] = lbl;
    red[wid * 3 + 2] = vct;
  }
  __syncthreads();
  if (tid == 0) {
    float a = red[0] + red[3] + red[6] + red[9];
    float c = red[1] + red[4] + red[7] + red[10];
    float v = red[2] + red[5] + red[8] + red[11];
    atomicAdd(&accum[0], a);
    atomicAdd(&accum[1], c);
    atomicAdd(&accum[2], v);
  }
}

extern "C" void kernel_launch(void* const* d_in, const int* in_sizes, int n_in,
                              void* d_out, int out_size, void* d_ws, size_t ws_size,
                              hipStream_t stream) {
  const float* pf  = (const float*)d_in[0];
  const float* of  = (const float*)d_in[1];
  const float* e1i = (const float*)d_in[2];
  const float* e1j = (const float*)d_in[3];
  const float* e2j = (const float*)d_in[4];

  char* base = (char*)d_ws;
  constexpr size_t NR = (size_t)BB * P;               // 32768 rows
  float* accum                 = (float*)base;                    // 64 B
  float* d_row                 = (float*)(base + 64);
  float* s1_row                = (float*)(base + 64 + 4 * NR);
  float* s2_row                = (float*)(base + 64 + 8 * NR);
  unsigned long long* pk_row   = (unsigned long long*)(base + 64 + 12 * NR);
  int* ip_row                  = (int*)(base + 64 + 20 * NR);
  __hip_bfloat16* pn           = (__hip_bfloat16*)(base + 64 + 24 * NR);
  const size_t pn_bytes = (size_t)BB * P * D * 2;
  const size_t on_bytes = (size_t)BB * O * D * 2;
  __hip_bfloat16* on           = (__hip_bfloat16*)(base + 64 + 24 * NR + pn_bytes);
  const size_t need = 64 + 24 * NR + pn_bytes + on_bytes;

  if (ws_size >= need) {
    hipMemsetAsync(base, 0, 64 + 20 * NR, stream);        // accum,d,s1,s2,pk
    hipMemsetAsync(ip_row, 0xFF, 4 * NR, stream);         // ip = -1
    prep_kernel<<<(BB * P + BB * O) / 4, 256, 0, stream>>>(pf, of, pn, on);
    icl_main7<<<BB * 72, 256, 0, stream>>>(pn, on, e1i, e1j, e2j,
                                           d_row, s1_row, s2_row, pk_row, ip_row);
    icl_reduce<<<NR / 256, 256, 0, stream>>>(d_row, s1_row, s2_row, pk_row,
                                             ip_row, accum);
  } else {
    float* ws   = (float*)d_ws;
    float* invp = ws + 16;
    float* invo = ws + 16 + BB * P;
    hipMemsetAsync(accum, 0, 16 * sizeof(float), stream);
    norm_kernel<<<(BB * P + BB * O) / 4, 256, 0, stream>>>(pf, of, invp, invo);
    icl_main_v1<<<BB * (P / 128), 256, 0, stream>>>(pf, of, e1i, e1j, e2j,
                                                    invp, invo, accum);
  }
  finalize_kernel<<<1, 64, 0, stream>>>(accum, (float*)d_out);
}